// Round 3
// baseline (640.108 us; speedup 1.0000x reference)
//
#include <hip/hip_runtime.h>

#define HH 8
#define NN 32
#define TT 2048
#define DD 256

typedef float f4 __attribute__((ext_vector_type(4)));
typedef float f32x4 __attribute__((ext_vector_type(4)));
typedef _Float16 f16x8 __attribute__((ext_vector_type(8)));
typedef unsigned short u16;
typedef u16 u16x8 __attribute__((ext_vector_type(8)));

__device__ __forceinline__ u16 f2h(float x) {
  _Float16 h = (_Float16)x;
  return *(u16*)&h;
}

__device__ __forceinline__ float ftanh(float x) {
  float ax = __builtin_fabsf(x);
  float e = __expf(ax + ax);
  float t = 1.f - 2.f / (e + 1.f);
  return x < 0.f ? -t : t;
}

__device__ __forceinline__ void gl_lds16(const void* g, void* l) {
  __builtin_amdgcn_global_load_lds((const __attribute__((address_space(1))) unsigned*)g,
                                   (__attribute__((address_space(3))) unsigned*)l, 16, 0, 0);
}

// ===========================================================================
// Packed operand layout (verified in R2; per 16KB region = [256 rows][32 k]):
//   line = row>>1 (128B lines, 8 slots of 16B);
//   slot pos = (ksl | ((row&1)<<2)) ^ (line&7)   (XOR bank swizzle);
//   within slot, u16 j holds k = ks*32 + ksl*4 + {0,1,2,3,16,17,18,19}[j]
//   (the kperm for mfma_f32_16x16x32 operand fragments).
// ===========================================================================

// mk [N][T][D] fp32 -> pa [ntb(256)][ks(8)][8192 u16]   (32MB)
__global__ void k_packA(const float* __restrict__ mk, u16* __restrict__ pa) {
  int u = blockIdx.x * 256 + threadIdx.x;   // 2,097,152 threads, 16B each
  int pos  = u & 7;
  int line = (u >> 3) & 127;
  int ks   = (u >> 10) & 7;
  int tb   = (u >> 13) & 7;
  int n    = u >> 16;
  int origpos = pos ^ (line & 7);
  int r   = (line << 1) + (origpos >> 2);
  int ksl = origpos & 3;
  int kb  = (ks << 5) + (ksl << 2);
  const float* src = mk + (((size_t)n * TT + (tb << 8) + r) << 8) + kb;
  f4 v0 = *(const f4*)src;
  f4 v1 = *(const f4*)(src + 16);
  u16 hv[8] = {f2h(v0.x), f2h(v0.y), f2h(v0.z), f2h(v0.w),
               f2h(v1.x), f2h(v1.y), f2h(v1.z), f2h(v1.w)};
  size_t dst = ((size_t)u & ~7ull) << 3;    // == ((ntb*8+ks)<<13)+(line<<6)
  *(u16x8*)(pa + dst + (pos << 3)) = *(u16x8*)hv;
}

// Wm [H][256 e][256 d] fp32 -> pb [h][ks(8)][8192 u16]   (1MB)
__global__ void k_packB(const float* __restrict__ wm, u16* __restrict__ pb) {
  int u = blockIdx.x * 256 + threadIdx.x;   // 65,536 threads
  int pos  = u & 7;
  int line = (u >> 3) & 127;
  int ks   = (u >> 10) & 7;
  int h    = u >> 13;
  int origpos = pos ^ (line & 7);
  int e   = (line << 1) + (origpos >> 2);
  int ksl = origpos & 3;
  int kb  = (ks << 5) + (ksl << 2);
  const float* src = wm + (((size_t)h * 256 + e) << 8) + kb;
  f4 v0 = *(const f4*)src;
  f4 v1 = *(const f4*)(src + 16);
  u16 hv[8] = {f2h(v0.x), f2h(v0.y), f2h(v0.z), f2h(v0.w),
               f2h(v1.x), f2h(v1.y), f2h(v1.z), f2h(v1.w)};
  size_t dst = ((size_t)u & ~7ull) << 3;
  *(u16x8*)(pb + dst + (pos << 3)) = *(u16x8*)hv;
}

// ---------------------------------------------------------------------------
// scores[h][n][t] = ok[n] . tanh(Wm[h] @ mk[n,t]), single-pass f16 MFMA.
// 512 thr (8 waves = 2m x 4n), tile 256t x 256e, BK=32, 8 steps.
// Proven m97-class 2-barrier schedule; both operands via global_load_lds.
// ---------------------------------------------------------------------------
__global__ __launch_bounds__(512, 4) void k_scoresf(
    const float* __restrict__ ok, const u16* __restrict__ pa,
    const u16* __restrict__ pb, float* __restrict__ sc) {
  __shared__ __align__(1024) u16 lds[16384];   // 32KB: A 16KB | B 16KB
  __shared__ float red[256][4];

  const int bid = blockIdx.x;
  const int g = ((bid & 7) << 8) + (bid >> 3);   // XCD-contiguous (2048%8==0)
  const int h = g & 7;
  const int ntb = g >> 3;
  const int n = ntb >> 3;
  const int tb = ntb & 7;
  const int tid = threadIdx.x;
  const int wave = tid >> 6;
  const int lane = tid & 63;
  const int wr = wave >> 2, wc = wave & 3;
  const int l15 = lane & 15, lg = lane >> 4;

  // fragment LDS offsets (u16 units)
  int Aoff[8], Boff[4];
#pragma unroll
  for (int mi = 0; mi < 8; ++mi) {
    int row = (wr << 7) + (mi << 4) + l15;
    int line = row >> 1;
    int pos = (lg | ((row & 1) << 2)) ^ (line & 7);
    Aoff[mi] = (line << 6) + (pos << 3);
  }
#pragma unroll
  for (int ni = 0; ni < 4; ++ni) {
    int e = (wc << 6) + (ni << 4) + l15;
    int line = e >> 1;
    int pos = (lg | ((e & 1) << 2)) ^ (line & 7);
    Boff[ni] = 8192 + (line << 6) + (pos << 3);
  }

  const u16* abase = pa + (size_t)ntb * 65536;
  const u16* bbase = pb + (size_t)h * 65536;

  f32x4 acc[8][4];
#pragma unroll
  for (int i = 0; i < 8; ++i)
#pragma unroll
    for (int j = 0; j < 4; ++j) acc[i][j] = (f32x4){0.f, 0.f, 0.f, 0.f};

  for (int ks = 0; ks < 8; ++ks) {
    __syncthreads();
    // stage A (chunks 0..15) + B (16..31), 1KB per chunk, 4 per thread
#pragma unroll
    for (int j = 0; j < 4; ++j) {
      const int c = (j << 3) + wave;
      const u16* src = (j < 2 ? abase + (ks << 13) + (c << 9)
                              : bbase + (ks << 13) + ((c - 16) << 9)) + (lane << 3);
      gl_lds16(src, &lds[c << 9]);
    }
    __syncthreads();   // compiler drains vmcnt(0) before this barrier

    bf16_dummy:;
    f16x8 bfr[4], afr[4];
#pragma unroll
    for (int ni = 0; ni < 4; ++ni) bfr[ni] = *(const f16x8*)&lds[Boff[ni]];
#pragma unroll
    for (int mi = 0; mi < 4; ++mi) afr[mi] = *(const f16x8*)&lds[Aoff[mi]];
#pragma unroll
    for (int mi = 0; mi < 4; ++mi)
#pragma unroll
      for (int ni = 0; ni < 4; ++ni)
        acc[mi][ni] = __builtin_amdgcn_mfma_f32_16x16x32_f16(afr[mi], bfr[ni], acc[mi][ni], 0, 0, 0);
#pragma unroll
    for (int mi = 0; mi < 4; ++mi) afr[mi] = *(const f16x8*)&lds[Aoff[mi + 4]];
#pragma unroll
    for (int mi = 0; mi < 4; ++mi)
#pragma unroll
      for (int ni = 0; ni < 4; ++ni)
        acc[mi + 4][ni] = __builtin_amdgcn_mfma_f32_16x16x32_f16(afr[mi], bfr[ni], acc[mi + 4][ni], 0, 0, 0);
  }

  // Epilogue: s[t] = sum_e tanh(P[t,e]) * ok[e]
  float okv[4];
#pragma unroll
  for (int ni = 0; ni < 4; ++ni) okv[ni] = ok[(n << 8) + (wc << 6) + (ni << 4) + l15];
#pragma unroll
  for (int mi = 0; mi < 8; ++mi) {
#pragma unroll
    for (int j = 0; j < 4; ++j) {
      float s = 0.f;
#pragma unroll
      for (int ni = 0; ni < 4; ++ni) s += ftanh(acc[mi][ni][j]) * okv[ni];
      s += __shfl_xor(s, 1);
      s += __shfl_xor(s, 2);
      s += __shfl_xor(s, 4);
      s += __shfl_xor(s, 8);
      if (l15 == 0) red[(wr << 7) + (mi << 4) + (lg << 2) + j][wc] = s;
    }
  }
  __syncthreads();
  if (tid < 256) {
    float v = red[tid][0] + red[tid][1] + red[tid][2] + red[tid][3];
    sc[(((size_t)h * 32 + n) << 11) + (tb << 8) + tid] = v;
  }
}

// ---------------------------------------------------------------------------
// Softmax over T per (h,n) row, in place.
// ---------------------------------------------------------------------------
__global__ void k_softmax(float* __restrict__ sc) {
  __shared__ float sm[8];
  const int row = blockIdx.x, tid = threadIdx.x;
  float* base = sc + ((size_t)row << 11);
  f4 a = *(const f4*)(base + tid * 8);
  f4 b = *(const f4*)(base + tid * 8 + 4);
  float m = fmaxf(fmaxf(fmaxf(a.x, a.y), fmaxf(a.z, a.w)),
                  fmaxf(fmaxf(b.x, b.y), fmaxf(b.z, b.w)));
#pragma unroll
  for (int o = 1; o < 64; o <<= 1) m = fmaxf(m, __shfl_xor(m, o));
  if ((tid & 63) == 0) sm[tid >> 6] = m;
  __syncthreads();
  m = fmaxf(fmaxf(sm[0], sm[1]), fmaxf(sm[2], sm[3]));
  a.x = __expf(a.x - m); a.y = __expf(a.y - m); a.z = __expf(a.z - m); a.w = __expf(a.w - m);
  b.x = __expf(b.x - m); b.y = __expf(b.y - m); b.z = __expf(b.z - m); b.w = __expf(b.w - m);
  float s = a.x + a.y + a.z + a.w + b.x + b.y + b.z + b.w;
#pragma unroll
  for (int o = 1; o < 64; o <<= 1) s += __shfl_xor(s, o);
  if ((tid & 63) == 0) sm[4 + (tid >> 6)] = s;
  __syncthreads();
  s = sm[4] + sm[5] + sm[6] + sm[7];
  float inv = 1.f / s;
  a.x *= inv; a.y *= inv; a.z *= inv; a.w *= inv;
  b.x *= inv; b.y *= inv; b.z *= inv; b.w *= inv;
  *(f4*)(base + tid * 8) = a;
  *(f4*)(base + tid * 8 + 4) = b;
}

// ---------------------------------------------------------------------------
// Partial rep over t-slices of 128: rp[n][sl][h*256+d]
// ---------------------------------------------------------------------------
__global__ void k_rep(const float* __restrict__ mv, const float* __restrict__ p,
                      float* __restrict__ rp) {
  __shared__ float pl[8][128];
  const int b = blockIdx.x;
  const int n = b >> 4, sl = b & 15;
  const int tid = threadIdx.x;
  for (int i = tid; i < 1024; i += 256) {
    int h = i >> 7, t = i & 127;
    pl[h][t] = p[(((size_t)h * 32 + n) << 11) + sl * 128 + t];
  }
  __syncthreads();
  float r[8] = {0.f, 0.f, 0.f, 0.f, 0.f, 0.f, 0.f, 0.f};
  const float* src = mv + (((size_t)n << 11) + sl * 128) * DD + tid;
#pragma unroll 4
  for (int tt = 0; tt < 128; ++tt) {
    float v = src[(size_t)tt * DD];
#pragma unroll
    for (int h = 0; h < 8; ++h) r[h] = fmaf(pl[h][tt], v, r[h]);
  }
  float* dst = rp + (((size_t)n * 16 + sl) << 11) + tid;
#pragma unroll
  for (int h = 0; h < 8; ++h) dst[h * 256] = r[h];
}

// ---------------------------------------------------------------------------
// out[n][i] = b[i] + sum_j concat[n][j] * Wo_w[i][j]
// ---------------------------------------------------------------------------
__global__ void k_out(const float* __restrict__ rp, const float* __restrict__ w,
                      const float* __restrict__ bias, float* __restrict__ out) {
  __shared__ float c[2048];
  const int n = blockIdx.x, tid = threadIdx.x;
  for (int j = tid; j < 2048; j += 256) {
    float s = 0.f;
#pragma unroll
    for (int sl = 0; sl < 16; ++sl) s += rp[(((size_t)n * 16 + sl) << 11) + j];
    c[j] = s;
  }
  __syncthreads();
  float acc = bias[tid];
  const f4* wrow = (const f4*)(w + (size_t)tid * 2048);
  const f4* cc = (const f4*)c;
  for (int j = 0; j < 512; ++j) {
    f4 wv = wrow[j];
    f4 cv = cc[j];
    acc += wv.x * cv.x + wv.y * cv.y + wv.z * cv.z + wv.w * cv.w;
  }
  out[n * 256 + tid] = acc;
}

extern "C" void kernel_launch(void* const* d_in, const int* in_sizes, int n_in,
                              void* d_out, int out_size, void* d_ws, size_t ws_size,
                              hipStream_t stream) {
  const float* ok  = (const float*)d_in[0];
  const float* mk  = (const float*)d_in[1];
  const float* mv  = (const float*)d_in[2];
  const float* wm  = (const float*)d_in[3];
  const float* wow = (const float*)d_in[4];
  const float* wob = (const float*)d_in[5];
  float* out = (float*)d_out;
  char* ws = (char*)d_ws;

  // ws: [0,2MB) scores | [2,3MB) packB | [4,8MB) rep partials | [16,48MB) packA
  float* sc = (float*)ws;
  u16* pb   = (u16*)(ws + (2u << 20));
  float* rp = (float*)(ws + (4u << 20));
  u16* pa   = (u16*)(ws + (16u << 20));

  hipLaunchKernelGGL(k_packA,   dim3(8192), dim3(256), 0, stream, mk, pa);
  hipLaunchKernelGGL(k_packB,   dim3(256),  dim3(256), 0, stream, wm, pb);
  hipLaunchKernelGGL(k_scoresf, dim3(2048), dim3(512), 0, stream, ok, pa, pb, sc);
  hipLaunchKernelGGL(k_softmax, dim3(256),  dim3(256), 0, stream, sc);
  hipLaunchKernelGGL(k_rep,     dim3(512),  dim3(256), 0, stream, mv, sc, rp);
  hipLaunchKernelGGL(k_out,     dim3(32),   dim3(256), 0, stream, rp, wow, wob, out);
}

// Round 4
// 266.592 us; speedup vs baseline: 2.4011x; 2.4011x over previous
//
#include <hip/hip_runtime.h>

#define HH 8
#define NN 32
#define TT 2048
#define DD 256

typedef float f4 __attribute__((ext_vector_type(4)));
typedef float f32x4 __attribute__((ext_vector_type(4)));
typedef _Float16 f16x8 __attribute__((ext_vector_type(8)));
typedef unsigned short u16;
typedef u16 u16x8 __attribute__((ext_vector_type(8)));

__device__ __forceinline__ u16 f2h(float x) {
  _Float16 h = (_Float16)x;
  return *(u16*)&h;
}

__device__ __forceinline__ float ftanh(float x) {
  float ax = __builtin_fabsf(x);
  float e = __expf(ax + ax);
  float t = 1.f - 2.f / (e + 1.f);
  return x < 0.f ? -t : t;
}

__device__ __forceinline__ void gl_lds16(const void* g, void* l) {
  __builtin_amdgcn_global_load_lds((const __attribute__((address_space(1))) unsigned*)g,
                                   (__attribute__((address_space(3))) unsigned*)l, 16, 0, 0);
}

// ===========================================================================
// Packed operand layout (numerically verified R2/R3; per 16KB region =
// [256 rows][32 k]):
//   line = row>>1 (128B lines, 8 slots of 16B);
//   slot pos = (ksl | ((row&1)<<2)) ^ (line&7)   (XOR bank swizzle);
//   within slot, u16 j holds k = ks*32 + ksl*4 + {0,1,2,3,16,17,18,19}[j]
//   (the kperm for mfma_f32_16x16x32 operand fragments).
// ===========================================================================

// mk [N][T][D] fp32 -> pa [ntb(256)][ks(8)][8192 u16]   (32MB)
__global__ void k_packA(const float* __restrict__ mk, u16* __restrict__ pa) {
  int u = blockIdx.x * 256 + threadIdx.x;   // 2,097,152 threads, 16B each
  int pos  = u & 7;
  int line = (u >> 3) & 127;
  int ks   = (u >> 10) & 7;
  int tb   = (u >> 13) & 7;
  int n    = u >> 16;
  int origpos = pos ^ (line & 7);
  int r   = (line << 1) + (origpos >> 2);
  int ksl = origpos & 3;
  int kb  = (ks << 5) + (ksl << 2);
  const float* src = mk + (((size_t)n * TT + (tb << 8) + r) << 8) + kb;
  f4 v0 = *(const f4*)src;
  f4 v1 = *(const f4*)(src + 16);
  u16 hv[8] = {f2h(v0.x), f2h(v0.y), f2h(v0.z), f2h(v0.w),
               f2h(v1.x), f2h(v1.y), f2h(v1.z), f2h(v1.w)};
  *(u16x8*)(pa + ((size_t)u << 3)) = *(u16x8*)hv;
}

// Wm [H][256 e][256 d] fp32 -> pb [h][ks(8)][8192 u16]   (1MB)
__global__ void k_packB(const float* __restrict__ wm, u16* __restrict__ pb) {
  int u = blockIdx.x * 256 + threadIdx.x;   // 65,536 threads
  int pos  = u & 7;
  int line = (u >> 3) & 127;
  int ks   = (u >> 10) & 7;
  int h    = u >> 13;
  int origpos = pos ^ (line & 7);
  int e   = (line << 1) + (origpos >> 2);
  int ksl = origpos & 3;
  int kb  = (ks << 5) + (ksl << 2);
  const float* src = wm + (((size_t)h * 256 + e) << 8) + kb;
  f4 v0 = *(const f4*)src;
  f4 v1 = *(const f4*)(src + 16);
  u16 hv[8] = {f2h(v0.x), f2h(v0.y), f2h(v0.z), f2h(v0.w),
               f2h(v1.x), f2h(v1.y), f2h(v1.z), f2h(v1.w)};
  *(u16x8*)(pb + ((size_t)u << 3)) = *(u16x8*)hv;
}

// ---------------------------------------------------------------------------
// scores[h][n][t] = ok[n] . tanh(Wm[h] @ mk[n,t]), single-pass f16 MFMA.
// 512 thr (8 waves = 2m x 4n), tile 256t x 256e, BK=32, 8 steps.
// 2-barrier m97-class schedule; both operands staged via global_load_lds.
// launch_bounds(512,2): 256 regs/wave -> acc[8][4] lives in regs (R3 spilled).
// Block map: h = bid&7 == XCD (B panel L2-resident per XCD); the 8 blocks
// sharing an A region dispatch together across the 8 XCDs.
// ---------------------------------------------------------------------------
__global__ __launch_bounds__(512, 2) void k_scoresf(
    const float* __restrict__ ok, const u16* __restrict__ pa,
    const u16* __restrict__ pb, float* __restrict__ sc) {
  __shared__ __align__(1024) u16 lds[16384];   // 32KB: A 16KB | B 16KB
  __shared__ float red[256][4];

  const int bid = blockIdx.x;
  const int h = bid & 7;            // == XCD (round-robin dispatch)
  const int ntb = bid >> 3;
  const int n = ntb >> 3;
  const int tb = ntb & 7;
  const int tid = threadIdx.x;
  const int wave = tid >> 6;
  const int lane = tid & 63;
  const int wr = wave >> 2, wc = wave & 3;
  const int l15 = lane & 15, lg = lane >> 4;

  // fragment LDS offsets (u16 units)
  int Aoff[8], Boff[4];
#pragma unroll
  for (int mi = 0; mi < 8; ++mi) {
    int row = (wr << 7) + (mi << 4) + l15;
    int line = row >> 1;
    int pos = (lg | ((row & 1) << 2)) ^ (line & 7);
    Aoff[mi] = (line << 6) + (pos << 3);
  }
#pragma unroll
  for (int ni = 0; ni < 4; ++ni) {
    int e = (wc << 6) + (ni << 4) + l15;
    int line = e >> 1;
    int pos = (lg | ((e & 1) << 2)) ^ (line & 7);
    Boff[ni] = 8192 + (line << 6) + (pos << 3);
  }

  const u16* abase = pa + (size_t)ntb * 65536;
  const u16* bbase = pb + (size_t)h * 65536;

  f32x4 acc[8][4];
#pragma unroll
  for (int i = 0; i < 8; ++i)
#pragma unroll
    for (int j = 0; j < 4; ++j) acc[i][j] = (f32x4){0.f, 0.f, 0.f, 0.f};

  for (int ks = 0; ks < 8; ++ks) {
    __syncthreads();
    // stage A (chunks 0..15) + B (16..31), 1KB per chunk, 4 per wave-slot
#pragma unroll
    for (int j = 0; j < 4; ++j) {
      const int c = (j << 3) + wave;
      const u16* src = (j < 2 ? abase + (ks << 13) + (c << 9)
                              : bbase + (ks << 13) + ((c - 16) << 9)) + (lane << 3);
      gl_lds16(src, &lds[c << 9]);
    }
    __syncthreads();   // compiler drains vmcnt(0) before this barrier

    f16x8 bfr[4], afr[4];
#pragma unroll
    for (int ni = 0; ni < 4; ++ni) bfr[ni] = *(const f16x8*)&lds[Boff[ni]];
#pragma unroll
    for (int mi = 0; mi < 4; ++mi) afr[mi] = *(const f16x8*)&lds[Aoff[mi]];
#pragma unroll
    for (int mi = 0; mi < 4; ++mi)
#pragma unroll
      for (int ni = 0; ni < 4; ++ni)
        acc[mi][ni] = __builtin_amdgcn_mfma_f32_16x16x32_f16(afr[mi], bfr[ni], acc[mi][ni], 0, 0, 0);
#pragma unroll
    for (int mi = 0; mi < 4; ++mi) afr[mi] = *(const f16x8*)&lds[Aoff[mi + 4]];
#pragma unroll
    for (int mi = 0; mi < 4; ++mi)
#pragma unroll
      for (int ni = 0; ni < 4; ++ni)
        acc[mi + 4][ni] = __builtin_amdgcn_mfma_f32_16x16x32_f16(afr[mi], bfr[ni], acc[mi + 4][ni], 0, 0, 0);
  }

  // Epilogue: s[t] = sum_e tanh(P[t,e]) * ok[e]
  float okv[4];
#pragma unroll
  for (int ni = 0; ni < 4; ++ni) okv[ni] = ok[(n << 8) + (wc << 6) + (ni << 4) + l15];
#pragma unroll
  for (int mi = 0; mi < 8; ++mi) {
#pragma unroll
    for (int j = 0; j < 4; ++j) {
      float s = 0.f;
#pragma unroll
      for (int ni = 0; ni < 4; ++ni) s += ftanh(acc[mi][ni][j]) * okv[ni];
      s += __shfl_xor(s, 1);
      s += __shfl_xor(s, 2);
      s += __shfl_xor(s, 4);
      s += __shfl_xor(s, 8);
      if (l15 == 0) red[(wr << 7) + (mi << 4) + (lg << 2) + j][wc] = s;
    }
  }
  __syncthreads();
  if (tid < 256) {
    float v = red[tid][0] + red[tid][1] + red[tid][2] + red[tid][3];
    sc[(((size_t)h * 32 + n) << 11) + (tb << 8) + tid] = v;
  }
}

// ---------------------------------------------------------------------------
// Softmax over T per (h,n) row, in place.
// ---------------------------------------------------------------------------
__global__ void k_softmax(float* __restrict__ sc) {
  __shared__ float sm[8];
  const int row = blockIdx.x, tid = threadIdx.x;
  float* base = sc + ((size_t)row << 11);
  f4 a = *(const f4*)(base + tid * 8);
  f4 b = *(const f4*)(base + tid * 8 + 4);
  float m = fmaxf(fmaxf(fmaxf(a.x, a.y), fmaxf(a.z, a.w)),
                  fmaxf(fmaxf(b.x, b.y), fmaxf(b.z, b.w)));
#pragma unroll
  for (int o = 1; o < 64; o <<= 1) m = fmaxf(m, __shfl_xor(m, o));
  if ((tid & 63) == 0) sm[tid >> 6] = m;
  __syncthreads();
  m = fmaxf(fmaxf(sm[0], sm[1]), fmaxf(sm[2], sm[3]));
  a.x = __expf(a.x - m); a.y = __expf(a.y - m); a.z = __expf(a.z - m); a.w = __expf(a.w - m);
  b.x = __expf(b.x - m); b.y = __expf(b.y - m); b.z = __expf(b.z - m); b.w = __expf(b.w - m);
  float s = a.x + a.y + a.z + a.w + b.x + b.y + b.z + b.w;
#pragma unroll
  for (int o = 1; o < 64; o <<= 1) s += __shfl_xor(s, o);
  if ((tid & 63) == 0) sm[4 + (tid >> 6)] = s;
  __syncthreads();
  s = sm[4] + sm[5] + sm[6] + sm[7];
  float inv = 1.f / s;
  a.x *= inv; a.y *= inv; a.z *= inv; a.w *= inv;
  b.x *= inv; b.y *= inv; b.z *= inv; b.w *= inv;
  *(f4*)(base + tid * 8) = a;
  *(f4*)(base + tid * 8 + 4) = b;
}

// ---------------------------------------------------------------------------
// Partial rep over t-slices of 128: rp[n][sl][h*256+d]
// ---------------------------------------------------------------------------
__global__ void k_rep(const float* __restrict__ mv, const float* __restrict__ p,
                      float* __restrict__ rp) {
  __shared__ float pl[8][128];
  const int b = blockIdx.x;
  const int n = b >> 4, sl = b & 15;
  const int tid = threadIdx.x;
  for (int i = tid; i < 1024; i += 256) {
    int h = i >> 7, t = i & 127;
    pl[h][t] = p[(((size_t)h * 32 + n) << 11) + sl * 128 + t];
  }
  __syncthreads();
  float r[8] = {0.f, 0.f, 0.f, 0.f, 0.f, 0.f, 0.f, 0.f};
  const float* src = mv + (((size_t)n << 11) + sl * 128) * DD + tid;
#pragma unroll 4
  for (int tt = 0; tt < 128; ++tt) {
    float v = src[(size_t)tt * DD];
#pragma unroll
    for (int h = 0; h < 8; ++h) r[h] = fmaf(pl[h][tt], v, r[h]);
  }
  float* dst = rp + (((size_t)n * 16 + sl) << 11) + tid;
#pragma unroll
  for (int h = 0; h < 8; ++h) dst[h * 256] = r[h];
}

// ---------------------------------------------------------------------------
// out[n][i] = b[i] + sum_j concat[n][j] * Wo_w[i][j]
// ---------------------------------------------------------------------------
__global__ void k_out(const float* __restrict__ rp, const float* __restrict__ w,
                      const float* __restrict__ bias, float* __restrict__ out) {
  __shared__ float c[2048];
  const int n = blockIdx.x, tid = threadIdx.x;
  for (int j = tid; j < 2048; j += 256) {
    float s = 0.f;
#pragma unroll
    for (int sl = 0; sl < 16; ++sl) s += rp[(((size_t)n * 16 + sl) << 11) + j];
    c[j] = s;
  }
  __syncthreads();
  float acc = bias[tid];
  const f4* wrow = (const f4*)(w + (size_t)tid * 2048);
  const f4* cc = (const f4*)c;
  for (int j = 0; j < 512; ++j) {
    f4 wv = wrow[j];
    f4 cv = cc[j];
    acc += wv.x * cv.x + wv.y * cv.y + wv.z * cv.z + wv.w * cv.w;
  }
  out[n * 256 + tid] = acc;
}

extern "C" void kernel_launch(void* const* d_in, const int* in_sizes, int n_in,
                              void* d_out, int out_size, void* d_ws, size_t ws_size,
                              hipStream_t stream) {
  const float* ok  = (const float*)d_in[0];
  const float* mk  = (const float*)d_in[1];
  const float* mv  = (const float*)d_in[2];
  const float* wm  = (const float*)d_in[3];
  const float* wow = (const float*)d_in[4];
  const float* wob = (const float*)d_in[5];
  float* out = (float*)d_out;
  char* ws = (char*)d_ws;

  // ws: [0,2MB) scores | [2,3MB) packB | [4,8MB) rep partials | [16,48MB) packA
  float* sc = (float*)ws;
  u16* pb   = (u16*)(ws + (2u << 20));
  float* rp = (float*)(ws + (4u << 20));
  u16* pa   = (u16*)(ws + (16u << 20));

  hipLaunchKernelGGL(k_packA,   dim3(8192), dim3(256), 0, stream, mk, pa);
  hipLaunchKernelGGL(k_packB,   dim3(256),  dim3(256), 0, stream, wm, pb);
  hipLaunchKernelGGL(k_scoresf, dim3(2048), dim3(512), 0, stream, ok, pa, pb, sc);
  hipLaunchKernelGGL(k_softmax, dim3(256),  dim3(256), 0, stream, sc);
  hipLaunchKernelGGL(k_rep,     dim3(512),  dim3(256), 0, stream, mv, sc, rp);
  hipLaunchKernelGGL(k_out,     dim3(32),   dim3(256), 0, stream, rp, wow, wob, out);
}

// Round 5
// 253.647 us; speedup vs baseline: 2.5236x; 1.0510x over previous
//
#include <hip/hip_runtime.h>

#define HH 8
#define NN 32
#define TT 2048
#define DD 256

typedef float f4 __attribute__((ext_vector_type(4)));
typedef float f32x4 __attribute__((ext_vector_type(4)));
typedef _Float16 f16x8 __attribute__((ext_vector_type(8)));
typedef unsigned short u16;
typedef u16 u16x8 __attribute__((ext_vector_type(8)));

__device__ __forceinline__ u16 f2h(float x) {
  _Float16 h = (_Float16)x;
  return *(u16*)&h;
}

__device__ __forceinline__ float ftanh(float x) {
  float ax = __builtin_fabsf(x);
  float e = __expf(ax + ax);
  float t = 1.f - 2.f / (e + 1.f);
  return x < 0.f ? -t : t;
}

__device__ __forceinline__ void gl_lds16(const void* g, void* l) {
  __builtin_amdgcn_global_load_lds((const __attribute__((address_space(1))) unsigned*)g,
                                   (__attribute__((address_space(3))) unsigned*)l, 16, 0, 0);
}

// ===========================================================================
// Packed operand layout (swizzle verified R2-R4), now 128-row regions:
// per 8KB region = [128 rows][32 k] f16:
//   line = row>>1 (128B lines of 8 x 16B slots), line in [0,64);
//   slot pos = (ksl | ((row&1)<<2)) ^ (line&7)   (XOR bank swizzle);
//   within slot, u16 j holds k = ks*32 + ksl*4 + {0,1,2,3,16,17,18,19}[j]
//   (kperm for mfma_f32_16x16x32 operand fragments).
// ===========================================================================

// mk [N][T][D] fp32 -> pa [n*16+tb][ks(8)][4096 u16]   (32MB)
__global__ void k_packA(const float* __restrict__ mk, u16* __restrict__ pa) {
  int u = blockIdx.x * 256 + threadIdx.x;   // 2,097,152 threads, 16B each
  int pos  = u & 7;
  int line = (u >> 3) & 63;
  int ks   = (u >> 9) & 7;
  int tb   = (u >> 12) & 15;
  int n    = u >> 16;
  int origpos = pos ^ (line & 7);
  int r   = (line << 1) + (origpos >> 2);   // 0..127
  int ksl = origpos & 3;
  int kb  = (ks << 5) + (ksl << 2);
  const float* src = mk + (((size_t)n * TT + (tb << 7) + r) << 8) + kb;
  f4 v0 = *(const f4*)src;
  f4 v1 = *(const f4*)(src + 16);
  u16 hv[8] = {f2h(v0.x), f2h(v0.y), f2h(v0.z), f2h(v0.w),
               f2h(v1.x), f2h(v1.y), f2h(v1.z), f2h(v1.w)};
  *(u16x8*)(pa + ((size_t)u << 3)) = *(u16x8*)hv;
}

// Wm [H][256 e][256 d] fp32 -> pb [h*2+eb][ks(8)][4096 u16]   (1MB)
__global__ void k_packB(const float* __restrict__ wm, u16* __restrict__ pb) {
  int u = blockIdx.x * 256 + threadIdx.x;   // 65,536 threads
  int pos  = u & 7;
  int line = (u >> 3) & 63;
  int ks   = (u >> 9) & 7;
  int eb   = (u >> 12) & 1;
  int h    = u >> 13;
  int origpos = pos ^ (line & 7);
  int el  = (line << 1) + (origpos >> 2);
  int e   = (eb << 7) + el;
  int ksl = origpos & 3;
  int kb  = (ks << 5) + (ksl << 2);
  const float* src = wm + (((size_t)h * 256 + e) << 8) + kb;
  f4 v0 = *(const f4*)src;
  f4 v1 = *(const f4*)(src + 16);
  u16 hv[8] = {f2h(v0.x), f2h(v0.y), f2h(v0.z), f2h(v0.w),
               f2h(v1.x), f2h(v1.y), f2h(v1.z), f2h(v1.w)};
  *(u16x8*)(pb + ((size_t)u << 3)) = *(u16x8*)hv;
}

// ---------------------------------------------------------------------------
// sc2[(h*32+n)*2+eb][t] = sum_{e in eb-half} tanh(Wm[h] @ mk[n,t])[e] * ok[n,e]
// m97-shape: 256 thr (4 waves = 2m x 2n), tile 128t x 128e, BK=32, 8 steps,
// acc[4][4] (~150 VGPR) -> 3 blocks/CU of UNsynchronized blocks for latency
// hiding (R4 failed at 1 block/CU: 512-thr block + 256-reg waves).
// ---------------------------------------------------------------------------
__global__ __launch_bounds__(256, 3) void k_scoresf(
    const float* __restrict__ ok, const u16* __restrict__ pa,
    const u16* __restrict__ pb, float* __restrict__ sc2) {
  __shared__ __align__(1024) u16 lds[8192];   // 16KB: A 8KB | B 8KB
  __shared__ float red[128][2];

  const int bid = blockIdx.x;
  const int h  = bid & 7;            // == XCD (round-robin dispatch)
  const int eb = (bid >> 3) & 1;
  const int tb = (bid >> 4) & 15;
  const int n  = bid >> 8;
  const int tid = threadIdx.x;
  const int wave = tid >> 6;
  const int lane = tid & 63;
  const int wr = wave >> 1, wc = wave & 1;
  const int l15 = lane & 15, lg = lane >> 4;

  // fragment LDS offsets (u16 units)
  int Aoff[4], Boff[4];
#pragma unroll
  for (int mi = 0; mi < 4; ++mi) {
    int row = (wr << 6) + (mi << 4) + l15;
    int line = row >> 1;
    int pos = (lg | ((row & 1) << 2)) ^ (line & 7);
    Aoff[mi] = (line << 6) + (pos << 3);
  }
#pragma unroll
  for (int ni = 0; ni < 4; ++ni) {
    int el = (wc << 6) + (ni << 4) + l15;
    int line = el >> 1;
    int pos = (lg | ((el & 1) << 2)) ^ (line & 7);
    Boff[ni] = 4096 + (line << 6) + (pos << 3);
  }

  const u16* abase = pa + ((size_t)(n * 16 + tb) << 15);
  const u16* bbase = pb + ((size_t)(h * 2 + eb) << 15);

  f32x4 acc[4][4];
#pragma unroll
  for (int i = 0; i < 4; ++i)
#pragma unroll
    for (int j = 0; j < 4; ++j) acc[i][j] = (f32x4){0.f, 0.f, 0.f, 0.f};

  for (int ks = 0; ks < 8; ++ks) {
    __syncthreads();
    // stage A (chunks 0..7) + B (8..15), 1KB per chunk, 4 per thread
#pragma unroll
    for (int j = 0; j < 4; ++j) {
      const int c = (j << 2) + wave;
      const u16* src = (j < 2 ? abase + (ks << 12) + (c << 9)
                              : bbase + (ks << 12) + ((c - 8) << 9)) + (lane << 3);
      gl_lds16(src, &lds[c << 9]);
    }
    __syncthreads();   // compiler drains vmcnt(0) before this barrier

    f16x8 afr[4], bfr[4];
#pragma unroll
    for (int ni = 0; ni < 4; ++ni) bfr[ni] = *(const f16x8*)&lds[Boff[ni]];
#pragma unroll
    for (int mi = 0; mi < 4; ++mi) afr[mi] = *(const f16x8*)&lds[Aoff[mi]];
#pragma unroll
    for (int mi = 0; mi < 4; ++mi)
#pragma unroll
      for (int ni = 0; ni < 4; ++ni)
        acc[mi][ni] = __builtin_amdgcn_mfma_f32_16x16x32_f16(afr[mi], bfr[ni], acc[mi][ni], 0, 0, 0);
  }

  // Epilogue: partial s[t] = sum_{e in this block's 128} tanh(P[t,e]) * ok[e]
  float okv[4];
#pragma unroll
  for (int ni = 0; ni < 4; ++ni)
    okv[ni] = ok[(n << 8) + (eb << 7) + (wc << 6) + (ni << 4) + l15];
#pragma unroll
  for (int mi = 0; mi < 4; ++mi) {
#pragma unroll
    for (int j = 0; j < 4; ++j) {
      float s = 0.f;
#pragma unroll
      for (int ni = 0; ni < 4; ++ni) s += ftanh(acc[mi][ni][j]) * okv[ni];
      s += __shfl_xor(s, 1);
      s += __shfl_xor(s, 2);
      s += __shfl_xor(s, 4);
      s += __shfl_xor(s, 8);
      if (l15 == 0) red[(wr << 6) + (mi << 4) + (lg << 2) + j][wc] = s;
    }
  }
  __syncthreads();
  if (tid < 128) {
    float v = red[tid][0] + red[tid][1];
    sc2[((size_t)((h * 32 + n) * 2 + eb) << 11) + (tb << 7) + tid] = v;
  }
}

// ---------------------------------------------------------------------------
// Softmax over T per (h,n) row: adds the two eb partials, result -> eb=0 slot.
// ---------------------------------------------------------------------------
__global__ void k_softmax(float* __restrict__ sc2) {
  __shared__ float sm[8];
  const int row = blockIdx.x, tid = threadIdx.x;
  float* b0 = sc2 + ((size_t)row << 12);
  const float* b1 = b0 + 2048;
  f4 a = *(const f4*)(b0 + tid * 8);
  f4 b = *(const f4*)(b0 + tid * 8 + 4);
  f4 a1 = *(const f4*)(b1 + tid * 8);
  f4 b1v = *(const f4*)(b1 + tid * 8 + 4);
  a.x += a1.x; a.y += a1.y; a.z += a1.z; a.w += a1.w;
  b.x += b1v.x; b.y += b1v.y; b.z += b1v.z; b.w += b1v.w;
  float m = fmaxf(fmaxf(fmaxf(a.x, a.y), fmaxf(a.z, a.w)),
                  fmaxf(fmaxf(b.x, b.y), fmaxf(b.z, b.w)));
#pragma unroll
  for (int o = 1; o < 64; o <<= 1) m = fmaxf(m, __shfl_xor(m, o));
  if ((tid & 63) == 0) sm[tid >> 6] = m;
  __syncthreads();
  m = fmaxf(fmaxf(sm[0], sm[1]), fmaxf(sm[2], sm[3]));
  a.x = __expf(a.x - m); a.y = __expf(a.y - m); a.z = __expf(a.z - m); a.w = __expf(a.w - m);
  b.x = __expf(b.x - m); b.y = __expf(b.y - m); b.z = __expf(b.z - m); b.w = __expf(b.w - m);
  float s = a.x + a.y + a.z + a.w + b.x + b.y + b.z + b.w;
#pragma unroll
  for (int o = 1; o < 64; o <<= 1) s += __shfl_xor(s, o);
  if ((tid & 63) == 0) sm[4 + (tid >> 6)] = s;
  __syncthreads();
  s = sm[4] + sm[5] + sm[6] + sm[7];
  float inv = 1.f / s;
  a.x *= inv; a.y *= inv; a.z *= inv; a.w *= inv;
  b.x *= inv; b.y *= inv; b.z *= inv; b.w *= inv;
  *(f4*)(b0 + tid * 8) = a;
  *(f4*)(b0 + tid * 8 + 4) = b;
}

// ---------------------------------------------------------------------------
// Partial rep over t-slices of 128: rp[n][sl][h*256+d]
// probs live at sc2 row stride 4096 (eb=0 slot).
// ---------------------------------------------------------------------------
__global__ void k_rep(const float* __restrict__ mv, const float* __restrict__ p,
                      float* __restrict__ rp) {
  __shared__ float pl[8][128];
  const int b = blockIdx.x;
  const int n = b >> 4, sl = b & 15;
  const int tid = threadIdx.x;
  for (int i = tid; i < 1024; i += 256) {
    int h = i >> 7, t = i & 127;
    pl[h][t] = p[(((size_t)h * 32 + n) << 12) + sl * 128 + t];
  }
  __syncthreads();
  float r[8] = {0.f, 0.f, 0.f, 0.f, 0.f, 0.f, 0.f, 0.f};
  const float* src = mv + (((size_t)n << 11) + sl * 128) * DD + tid;
#pragma unroll 4
  for (int tt = 0; tt < 128; ++tt) {
    float v = src[(size_t)tt * DD];
#pragma unroll
    for (int h = 0; h < 8; ++h) r[h] = fmaf(pl[h][tt], v, r[h]);
  }
  float* dst = rp + (((size_t)n * 16 + sl) << 11) + tid;
#pragma unroll
  for (int h = 0; h < 8; ++h) dst[h * 256] = r[h];
}

// ---------------------------------------------------------------------------
// out[n][i] = b[i] + sum_j concat[n][j] * Wo_w[i][j]
// ---------------------------------------------------------------------------
__global__ void k_out(const float* __restrict__ rp, const float* __restrict__ w,
                      const float* __restrict__ bias, float* __restrict__ out) {
  __shared__ float c[2048];
  const int n = blockIdx.x, tid = threadIdx.x;
  for (int j = tid; j < 2048; j += 256) {
    float s = 0.f;
#pragma unroll
    for (int sl = 0; sl < 16; ++sl) s += rp[(((size_t)n * 16 + sl) << 11) + j];
    c[j] = s;
  }
  __syncthreads();
  float acc = bias[tid];
  const f4* wrow = (const f4*)(w + (size_t)tid * 2048);
  const f4* cc = (const f4*)c;
  for (int j = 0; j < 512; ++j) {
    f4 wv = wrow[j];
    f4 cv = cc[j];
    acc += wv.x * cv.x + wv.y * cv.y + wv.z * cv.z + wv.w * cv.w;
  }
  out[n * 256 + tid] = acc;
}

extern "C" void kernel_launch(void* const* d_in, const int* in_sizes, int n_in,
                              void* d_out, int out_size, void* d_ws, size_t ws_size,
                              hipStream_t stream) {
  const float* ok  = (const float*)d_in[0];
  const float* mk  = (const float*)d_in[1];
  const float* mv  = (const float*)d_in[2];
  const float* wm  = (const float*)d_in[3];
  const float* wow = (const float*)d_in[4];
  const float* wob = (const float*)d_in[5];
  float* out = (float*)d_out;
  char* ws = (char*)d_ws;

  // ws: [0,4MB) sc2 partials/probs | [4,5MB) packB | [8,16MB) rep | [16,48MB) packA
  float* sc2 = (float*)ws;
  u16* pb    = (u16*)(ws + (4u << 20));
  float* rp  = (float*)(ws + (8u << 20));
  u16* pa    = (u16*)(ws + (16u << 20));

  hipLaunchKernelGGL(k_packA,   dim3(8192), dim3(256), 0, stream, mk, pa);
  hipLaunchKernelGGL(k_packB,   dim3(256),  dim3(256), 0, stream, wm, pb);
  hipLaunchKernelGGL(k_scoresf, dim3(8192), dim3(256), 0, stream, ok, pa, pb, sc2);
  hipLaunchKernelGGL(k_softmax, dim3(256),  dim3(256), 0, stream, sc2);
  hipLaunchKernelGGL(k_rep,     dim3(512),  dim3(256), 0, stream, mv, sc2, rp);
  hipLaunchKernelGGL(k_out,     dim3(32),   dim3(256), 0, stream, rp, wow, wob, out);
}

// Round 6
// 253.518 us; speedup vs baseline: 2.5249x; 1.0005x over previous
//
#include <hip/hip_runtime.h>

#define HH 8
#define NN 32
#define TT 2048
#define DD 256

typedef float f4 __attribute__((ext_vector_type(4)));
typedef float f32x4 __attribute__((ext_vector_type(4)));
typedef _Float16 f16x8 __attribute__((ext_vector_type(8)));
typedef unsigned short u16;
typedef u16 u16x8 __attribute__((ext_vector_type(8)));

__device__ __forceinline__ u16 f2h(float x) {
  _Float16 h = (_Float16)x;
  return *(u16*)&h;
}

// Fast tanh: t = 1 - 2*rcp(exp(2|x|)+1), sign via bfi. ~9 cheap VALU ops,
// no precise-division sequence (R5: that sequence was 65% VALUBusy).
// exp overflow for |x|>44 -> rcp(inf)=0 -> t=1: correct saturation.
__device__ __forceinline__ float ftanh(float x) {
  float ax = __builtin_fabsf(x);
  float e = __expf(ax + ax);                      // native v_exp path
  float t = 1.f - __fdividef(2.f, e + 1.f);       // v_rcp + v_mul
  return __builtin_copysignf(t, x);               // v_bfi_b32
}

__device__ __forceinline__ void gl_lds16(const void* g, void* l) {
  __builtin_amdgcn_global_load_lds((const __attribute__((address_space(1))) unsigned*)g,
                                   (__attribute__((address_space(3))) unsigned*)l, 16, 0, 0);
}

// ===========================================================================
// Packed operand layout (swizzle verified R2-R5), 128-row regions:
// per 8KB region = [128 rows][32 k] f16:
//   line = row>>1 (128B lines of 8 x 16B slots), line in [0,64);
//   slot pos = (ksl | ((row&1)<<2)) ^ (line&7)   (XOR bank swizzle);
//   within slot, u16 j holds k = ks*32 + ksl*4 + {0,1,2,3,16,17,18,19}[j]
//   (kperm for mfma_f32_16x16x32 operand fragments).
// ===========================================================================

// mk [N][T][D] fp32 -> pa [n*16+tb][ks(8)][4096 u16]   (32MB)
__global__ void k_packA(const float* __restrict__ mk, u16* __restrict__ pa) {
  int u = blockIdx.x * 256 + threadIdx.x;   // 2,097,152 threads, 16B each
  int pos  = u & 7;
  int line = (u >> 3) & 63;
  int ks   = (u >> 9) & 7;
  int tb   = (u >> 12) & 15;
  int n    = u >> 16;
  int origpos = pos ^ (line & 7);
  int r   = (line << 1) + (origpos >> 2);   // 0..127
  int ksl = origpos & 3;
  int kb  = (ks << 5) + (ksl << 2);
  const float* src = mk + (((size_t)n * TT + (tb << 7) + r) << 8) + kb;
  f4 v0 = *(const f4*)src;
  f4 v1 = *(const f4*)(src + 16);
  u16 hv[8] = {f2h(v0.x), f2h(v0.y), f2h(v0.z), f2h(v0.w),
               f2h(v1.x), f2h(v1.y), f2h(v1.z), f2h(v1.w)};
  *(u16x8*)(pa + ((size_t)u << 3)) = *(u16x8*)hv;
}

// Wm [H][256 e][256 d] fp32 -> pb [h*2+eb][ks(8)][4096 u16]   (1MB)
__global__ void k_packB(const float* __restrict__ wm, u16* __restrict__ pb) {
  int u = blockIdx.x * 256 + threadIdx.x;   // 65,536 threads
  int pos  = u & 7;
  int line = (u >> 3) & 63;
  int ks   = (u >> 9) & 7;
  int eb   = (u >> 12) & 1;
  int h    = u >> 13;
  int origpos = pos ^ (line & 7);
  int el  = (line << 1) + (origpos >> 2);
  int e   = (eb << 7) + el;
  int ksl = origpos & 3;
  int kb  = (ks << 5) + (ksl << 2);
  const float* src = wm + (((size_t)h * 256 + e) << 8) + kb;
  f4 v0 = *(const f4*)src;
  f4 v1 = *(const f4*)(src + 16);
  u16 hv[8] = {f2h(v0.x), f2h(v0.y), f2h(v0.z), f2h(v0.w),
               f2h(v1.x), f2h(v1.y), f2h(v1.z), f2h(v1.w)};
  *(u16x8*)(pb + ((size_t)u << 3)) = *(u16x8*)hv;
}

// ---------------------------------------------------------------------------
// sc2[(h*32+n)*2+eb][t] = sum_{e in eb-half} tanh(Wm[h] @ mk[n,t])[e] * ok[n,e]
// m97-shape: 256 thr (4 waves = 2m x 2n), tile 128t x 128e, BK=32, 8 steps,
// acc[4][4] -> 3 blocks/CU of unsynchronized blocks for latency hiding.
// ---------------------------------------------------------------------------
__global__ __launch_bounds__(256, 3) void k_scoresf(
    const float* __restrict__ ok, const u16* __restrict__ pa,
    const u16* __restrict__ pb, float* __restrict__ sc2) {
  __shared__ __align__(1024) u16 lds[8192];   // 16KB: A 8KB | B 8KB
  __shared__ float red[128][2];

  const int bid = blockIdx.x;
  const int h  = bid & 7;            // == XCD (round-robin dispatch)
  const int eb = (bid >> 3) & 1;
  const int tb = (bid >> 4) & 15;
  const int n  = bid >> 8;
  const int tid = threadIdx.x;
  const int wave = tid >> 6;
  const int lane = tid & 63;
  const int wr = wave >> 1, wc = wave & 1;
  const int l15 = lane & 15, lg = lane >> 4;

  // fragment LDS offsets (u16 units)
  int Aoff[4], Boff[4];
#pragma unroll
  for (int mi = 0; mi < 4; ++mi) {
    int row = (wr << 6) + (mi << 4) + l15;
    int line = row >> 1;
    int pos = (lg | ((row & 1) << 2)) ^ (line & 7);
    Aoff[mi] = (line << 6) + (pos << 3);
  }
#pragma unroll
  for (int ni = 0; ni < 4; ++ni) {
    int el = (wc << 6) + (ni << 4) + l15;
    int line = el >> 1;
    int pos = (lg | ((el & 1) << 2)) ^ (line & 7);
    Boff[ni] = 4096 + (line << 6) + (pos << 3);
  }

  const u16* abase = pa + ((size_t)(n * 16 + tb) << 15);
  const u16* bbase = pb + ((size_t)(h * 2 + eb) << 15);

  f32x4 acc[4][4];
#pragma unroll
  for (int i = 0; i < 4; ++i)
#pragma unroll
    for (int j = 0; j < 4; ++j) acc[i][j] = (f32x4){0.f, 0.f, 0.f, 0.f};

  for (int ks = 0; ks < 8; ++ks) {
    __syncthreads();
    // stage A (chunks 0..7) + B (8..15), 1KB per chunk
#pragma unroll
    for (int j = 0; j < 4; ++j) {
      const int c = (j << 2) + wave;
      const u16* src = (j < 2 ? abase + (ks << 12) + (c << 9)
                              : bbase + (ks << 12) + ((c - 8) << 9)) + (lane << 3);
      gl_lds16(src, &lds[c << 9]);
    }
    __syncthreads();   // compiler drains vmcnt(0) before this barrier

    f16x8 afr[4], bfr[4];
#pragma unroll
    for (int ni = 0; ni < 4; ++ni) bfr[ni] = *(const f16x8*)&lds[Boff[ni]];
#pragma unroll
    for (int mi = 0; mi < 4; ++mi) afr[mi] = *(const f16x8*)&lds[Aoff[mi]];
#pragma unroll
    for (int mi = 0; mi < 4; ++mi)
#pragma unroll
      for (int ni = 0; ni < 4; ++ni)
        acc[mi][ni] = __builtin_amdgcn_mfma_f32_16x16x32_f16(afr[mi], bfr[ni], acc[mi][ni], 0, 0, 0);
  }

  // Epilogue: partial s[t] = sum_{e in this block's 128} tanh(P[t,e]) * ok[e]
  float okv[4];
#pragma unroll
  for (int ni = 0; ni < 4; ++ni)
    okv[ni] = ok[(n << 8) + (eb << 7) + (wc << 6) + (ni << 4) + l15];
#pragma unroll
  for (int mi = 0; mi < 4; ++mi) {
#pragma unroll
    for (int j = 0; j < 4; ++j) {
      float s = 0.f;
#pragma unroll
      for (int ni = 0; ni < 4; ++ni) s += ftanh(acc[mi][ni][j]) * okv[ni];
      s += __shfl_xor(s, 1);
      s += __shfl_xor(s, 2);
      s += __shfl_xor(s, 4);
      s += __shfl_xor(s, 8);
      if (l15 == 0) red[(wr << 6) + (mi << 4) + (lg << 2) + j][wc] = s;
    }
  }
  __syncthreads();
  if (tid < 128) {
    float v = red[tid][0] + red[tid][1];
    sc2[((size_t)((h * 32 + n) * 2 + eb) << 11) + (tb << 7) + tid] = v;
  }
}

// ---------------------------------------------------------------------------
// Softmax over T per (h,n) row: adds the two eb partials, result -> eb=0 slot.
// ---------------------------------------------------------------------------
__global__ void k_softmax(float* __restrict__ sc2) {
  __shared__ float sm[8];
  const int row = blockIdx.x, tid = threadIdx.x;
  float* b0 = sc2 + ((size_t)row << 12);
  const float* b1 = b0 + 2048;
  f4 a = *(const f4*)(b0 + tid * 8);
  f4 b = *(const f4*)(b0 + tid * 8 + 4);
  f4 a1 = *(const f4*)(b1 + tid * 8);
  f4 b1v = *(const f4*)(b1 + tid * 8 + 4);
  a.x += a1.x; a.y += a1.y; a.z += a1.z; a.w += a1.w;
  b.x += b1v.x; b.y += b1v.y; b.z += b1v.z; b.w += b1v.w;
  float m = fmaxf(fmaxf(fmaxf(a.x, a.y), fmaxf(a.z, a.w)),
                  fmaxf(fmaxf(b.x, b.y), fmaxf(b.z, b.w)));
#pragma unroll
  for (int o = 1; o < 64; o <<= 1) m = fmaxf(m, __shfl_xor(m, o));
  if ((tid & 63) == 0) sm[tid >> 6] = m;
  __syncthreads();
  m = fmaxf(fmaxf(sm[0], sm[1]), fmaxf(sm[2], sm[3]));
  a.x = __expf(a.x - m); a.y = __expf(a.y - m); a.z = __expf(a.z - m); a.w = __expf(a.w - m);
  b.x = __expf(b.x - m); b.y = __expf(b.y - m); b.z = __expf(b.z - m); b.w = __expf(b.w - m);
  float s = a.x + a.y + a.z + a.w + b.x + b.y + b.z + b.w;
#pragma unroll
  for (int o = 1; o < 64; o <<= 1) s += __shfl_xor(s, o);
  if ((tid & 63) == 0) sm[4 + (tid >> 6)] = s;
  __syncthreads();
  s = sm[4] + sm[5] + sm[6] + sm[7];
  float inv = 1.f / s;
  a.x *= inv; a.y *= inv; a.z *= inv; a.w *= inv;
  b.x *= inv; b.y *= inv; b.z *= inv; b.w *= inv;
  *(f4*)(b0 + tid * 8) = a;
  *(f4*)(b0 + tid * 8 + 4) = b;
}

// ---------------------------------------------------------------------------
// Partial rep over t-slices of 128: rp[n][sl][h*256+d]
// probs live at sc2 row stride 4096 (eb=0 slot).
// ---------------------------------------------------------------------------
__global__ void k_rep(const float* __restrict__ mv, const float* __restrict__ p,
                      float* __restrict__ rp) {
  __shared__ float pl[8][128];
  const int b = blockIdx.x;
  const int n = b >> 4, sl = b & 15;
  const int tid = threadIdx.x;
  for (int i = tid; i < 1024; i += 256) {
    int h = i >> 7, t = i & 127;
    pl[h][t] = p[(((size_t)h * 32 + n) << 12) + sl * 128 + t];
  }
  __syncthreads();
  float r[8] = {0.f, 0.f, 0.f, 0.f, 0.f, 0.f, 0.f, 0.f};
  const float* src = mv + (((size_t)n << 11) + sl * 128) * DD + tid;
#pragma unroll 4
  for (int tt = 0; tt < 128; ++tt) {
    float v = src[(size_t)tt * DD];
#pragma unroll
    for (int h = 0; h < 8; ++h) r[h] = fmaf(pl[h][tt], v, r[h]);
  }
  float* dst = rp + (((size_t)n * 16 + sl) << 11) + tid;
#pragma unroll
  for (int h = 0; h < 8; ++h) dst[h * 256] = r[h];
}

// ---------------------------------------------------------------------------
// out[n][i] = b[i] + sum_j concat[n][j] * Wo_w[i][j]
// ---------------------------------------------------------------------------
__global__ void k_out(const float* __restrict__ rp, const float* __restrict__ w,
                      const float* __restrict__ bias, float* __restrict__ out) {
  __shared__ float c[2048];
  const int n = blockIdx.x, tid = threadIdx.x;
  for (int j = tid; j < 2048; j += 256) {
    float s = 0.f;
#pragma unroll
    for (int sl = 0; sl < 16; ++sl) s += rp[(((size_t)n * 16 + sl) << 11) + j];
    c[j] = s;
  }
  __syncthreads();
  float acc = bias[tid];
  const f4* wrow = (const f4*)(w + (size_t)tid * 2048);
  const f4* cc = (const f4*)c;
  for (int j = 0; j < 512; ++j) {
    f4 wv = wrow[j];
    f4 cv = cc[j];
    acc += wv.x * cv.x + wv.y * cv.y + wv.z * cv.z + wv.w * cv.w;
  }
  out[n * 256 + tid] = acc;
}

extern "C" void kernel_launch(void* const* d_in, const int* in_sizes, int n_in,
                              void* d_out, int out_size, void* d_ws, size_t ws_size,
                              hipStream_t stream) {
  const float* ok  = (const float*)d_in[0];
  const float* mk  = (const float*)d_in[1];
  const float* mv  = (const float*)d_in[2];
  const float* wm  = (const float*)d_in[3];
  const float* wow = (const float*)d_in[4];
  const float* wob = (const float*)d_in[5];
  float* out = (float*)d_out;
  char* ws = (char*)d_ws;

  // ws: [0,4MB) sc2 partials/probs | [4,5MB) packB | [8,16MB) rep | [16,48MB) packA
  float* sc2 = (float*)ws;
  u16* pb    = (u16*)(ws + (4u << 20));
  float* rp  = (float*)(ws + (8u << 20));
  u16* pa    = (u16*)(ws + (16u << 20));

  hipLaunchKernelGGL(k_packA,   dim3(8192), dim3(256), 0, stream, mk, pa);
  hipLaunchKernelGGL(k_packB,   dim3(256),  dim3(256), 0, stream, wm, pb);
  hipLaunchKernelGGL(k_scoresf, dim3(8192), dim3(256), 0, stream, ok, pa, pb, sc2);
  hipLaunchKernelGGL(k_softmax, dim3(256),  dim3(256), 0, stream, sc2);
  hipLaunchKernelGGL(k_rep,     dim3(512),  dim3(256), 0, stream, mv, sc2, rp);
  hipLaunchKernelGGL(k_out,     dim3(32),   dim3(256), 0, stream, rp, wow, wob, out);
}

// Round 7
// 221.887 us; speedup vs baseline: 2.8848x; 1.1426x over previous
//
#include <hip/hip_runtime.h>

#define HH 8
#define NN 32
#define TT 2048
#define DD 256

typedef float f4 __attribute__((ext_vector_type(4)));
typedef float f32x4 __attribute__((ext_vector_type(4)));
typedef _Float16 f16x8 __attribute__((ext_vector_type(8)));
typedef unsigned short u16;
typedef u16 u16x8 __attribute__((ext_vector_type(8)));

__device__ __forceinline__ u16 f2h(float x) {
  _Float16 h = (_Float16)x;
  return *(u16*)&h;
}

// Fast tanh: 1 - 2*rcp(exp(2|x|)+1), sign via copysign. 2 trans + ~6 full-rate.
__device__ __forceinline__ float ftanh(float x) {
  float ax = __builtin_fabsf(x);
  float e = __expf(ax + ax);
  float t = 1.f - __fdividef(2.f, e + 1.f);
  return __builtin_copysignf(t, x);
}

__device__ __forceinline__ void gl_lds16(const void* g, void* l) {
  __builtin_amdgcn_global_load_lds((const __attribute__((address_space(1))) unsigned*)g,
                                   (__attribute__((address_space(3))) unsigned*)l, 16, 0, 0);
}

// ===========================================================================
// Packed operand layout (verified R2-R6), 128-row regions:
// per 8KB region = [128 rows][32 k] f16:
//   line = row>>1 (128B lines of 8 x 16B slots), line in [0,64);
//   slot pos = (ksl | ((row&1)<<2)) ^ (line&7)   (XOR bank swizzle);
//   within slot, u16 j holds k = ks*32 + ksl*4 + {0,1,2,3,16,17,18,19}[j]
//   (k-pattern of mfma_f32_16x16x32 operand fragments, verified R0/R1).
// Regions are operand-role agnostic ([row][k]); row = the non-K dim.
// ===========================================================================

// Merged pack: bid<8192 -> mk [N][T][D] -> pa [n*16+tb][ks(8)][4096 u16] (32MB)
//              bid>=8192 -> Wm [H][256e][256d] -> pb [h*2+eb][ks(8)][4096 u16] (1MB)
__global__ void k_pack(const float* __restrict__ mk, const float* __restrict__ wm,
                       u16* __restrict__ pa, u16* __restrict__ pb) {
  const int bid = blockIdx.x;
  if (bid < 8192) {
    int u = bid * 256 + threadIdx.x;
    int pos  = u & 7;
    int line = (u >> 3) & 63;
    int ks   = (u >> 9) & 7;
    int tb   = (u >> 12) & 15;
    int n    = u >> 16;
    int origpos = pos ^ (line & 7);
    int r   = (line << 1) + (origpos >> 2);
    int ksl = origpos & 3;
    int kb  = (ks << 5) + (ksl << 2);
    const float* src = mk + (((size_t)n * TT + (tb << 7) + r) << 8) + kb;
    f4 v0 = *(const f4*)src;
    f4 v1 = *(const f4*)(src + 16);
    u16 hv[8] = {f2h(v0.x), f2h(v0.y), f2h(v0.z), f2h(v0.w),
                 f2h(v1.x), f2h(v1.y), f2h(v1.z), f2h(v1.w)};
    *(u16x8*)(pa + ((size_t)u << 3)) = *(u16x8*)hv;
  } else {
    int u = (bid - 8192) * 256 + threadIdx.x;
    int pos  = u & 7;
    int line = (u >> 3) & 63;
    int ks   = (u >> 9) & 7;
    int eb   = (u >> 12) & 1;
    int h    = u >> 13;
    int origpos = pos ^ (line & 7);
    int el  = (line << 1) + (origpos >> 2);
    int e   = (eb << 7) + el;
    int ksl = origpos & 3;
    int kb  = (ks << 5) + (ksl << 2);
    const float* src = wm + (((size_t)h * 256 + e) << 8) + kb;
    f4 v0 = *(const f4*)src;
    f4 v1 = *(const f4*)(src + 16);
    u16 hv[8] = {f2h(v0.x), f2h(v0.y), f2h(v0.z), f2h(v0.w),
                 f2h(v1.x), f2h(v1.y), f2h(v1.z), f2h(v1.w)};
    *(u16x8*)(pb + ((size_t)u << 3)) = *(u16x8*)hv;
  }
}

// ---------------------------------------------------------------------------
// sc2[(h*32+n)*2+eb][t] = sum_{e in eb-half} tanh(Wm[h] @ mk[n,t])[e] * ok[n,e]
// SWAPPED operands: A=Wm (M=e 128), B=mk (N=t 128) -> acc = P^T[e][t].
// Epilogue dot over e done with a SECOND MFMA (acc regs are lane-local
// B-operand k-fragments); no shfl-reduce.
// Double-buffered LDS, stage(k+1) issued before compute(k): 1 barrier/step.
// ---------------------------------------------------------------------------
__global__ __launch_bounds__(256, 3) void k_scoresf(
    const float* __restrict__ ok, const u16* __restrict__ pa,
    const u16* __restrict__ pb, float* __restrict__ sc2) {
  __shared__ __align__(1024) u16 lds[2][8192];  // 2 x (mk 8KB | Wm 8KB)
  __shared__ float red[128][2];

  const int bid = blockIdx.x;
  const int h  = bid & 7;            // == XCD
  const int eb = (bid >> 3) & 1;
  const int tb = (bid >> 4) & 15;
  const int n  = bid >> 8;
  const int tid = threadIdx.x;
  const int wave = tid >> 6;
  const int lane = tid & 63;
  const int wr = wave >> 1, wc = wave & 1;   // wr: e-half, wc: t-half
  const int l15 = lane & 15, lg = lane >> 4;

  // fragment LDS offsets (u16 units): Wm = A operand (rows e), mk = B (rows t)
  int Woff[4], Moff[4];
#pragma unroll
  for (int mi = 0; mi < 4; ++mi) {
    int row = (wr << 6) + (mi << 4) + l15;
    int line = row >> 1;
    int pos = (lg | ((row & 1) << 2)) ^ (line & 7);
    Woff[mi] = 4096 + (line << 6) + (pos << 3);
  }
#pragma unroll
  for (int ni = 0; ni < 4; ++ni) {
    int row = (wc << 6) + (ni << 4) + l15;
    int line = row >> 1;
    int pos = (lg | ((row & 1) << 2)) ^ (line & 7);
    Moff[ni] = (line << 6) + (pos << 3);
  }

  const u16* abase = pa + ((size_t)(n * 16 + tb) << 15);
  const u16* bbase = pb + ((size_t)(h * 2 + eb) << 15);

  auto stage = [&](int ks, int cur) {
    u16* dst = &lds[cur][0];
#pragma unroll
    for (int j = 0; j < 4; ++j) {
      const int c = (j << 2) + wave;   // mk chunks 0..7, Wm chunks 8..15
      const u16* src = (j < 2 ? abase + (ks << 12) + (c << 9)
                              : bbase + (ks << 12) + ((c - 8) << 9)) + (lane << 3);
      gl_lds16(src, dst + (c << 9));
    }
  };

  f32x4 acc[4][4];
#pragma unroll
  for (int i = 0; i < 4; ++i)
#pragma unroll
    for (int j = 0; j < 4; ++j) acc[i][j] = (f32x4){0.f, 0.f, 0.f, 0.f};

  stage(0, 0);
  __syncthreads();                    // drains vmcnt(0)
#pragma unroll 1
  for (int ks = 0; ks < 8; ++ks) {
    const int cur = ks & 1;
    if (ks < 7) stage(ks + 1, cur ^ 1);   // overlap next-step loads w/ compute
    f16x8 wfr[4], mfr[4];
#pragma unroll
    for (int mi = 0; mi < 4; ++mi) wfr[mi] = *(const f16x8*)&lds[cur][Woff[mi]];
#pragma unroll
    for (int ni = 0; ni < 4; ++ni) mfr[ni] = *(const f16x8*)&lds[cur][Moff[ni]];
#pragma unroll
    for (int mi = 0; mi < 4; ++mi)
#pragma unroll
      for (int ni = 0; ni < 4; ++ni)
        acc[mi][ni] = __builtin_amdgcn_mfma_f32_16x16x32_f16(wfr[mi], mfr[ni], acc[mi][ni], 0, 0, 0);
    __syncthreads();                  // drains stage's vmcnt + sync reads
  }

  // Epilogue: S_partial[t] = sum_e tanh(P^T[e][t]) * ok[e]  via MFMA.
  // acc lane layout: e_row = mi*16 + lg*4 + j, t_col = l15 (verified C/D map).
  // B2 frag for (ni,q): elem b -> tanh(acc[2q+(b>>2)][ni][b&3]); k-pattern
  // k = lg*4 + (b&3) + 16*(b>>2) matches e rows lane-locally.
#pragma unroll
  for (int mi = 0; mi < 4; ++mi)
#pragma unroll
    for (int ni = 0; ni < 4; ++ni)
#pragma unroll
      for (int j = 0; j < 4; ++j) acc[mi][ni][j] = ftanh(acc[mi][ni][j]);

  // ok A-fragments (rows replicated): elem b -> ok[e_base + q*32 + lg*4 + (b&3) + 16*(b>>2)]
  f16x8 a2[2];
#pragma unroll
  for (int q = 0; q < 2; ++q) {
    const float* okb = ok + (n << 8) + (eb << 7) + (wr << 6) + (q << 5) + (lg << 2);
#pragma unroll
    for (int b = 0; b < 8; ++b)
      a2[q][b] = (_Float16)okb[(b & 3) + ((b >> 2) << 4)];
  }

  f32x4 d2[4];
#pragma unroll
  for (int ni = 0; ni < 4; ++ni) d2[ni] = (f32x4){0.f, 0.f, 0.f, 0.f};
#pragma unroll
  for (int ni = 0; ni < 4; ++ni) {
#pragma unroll
    for (int q = 0; q < 2; ++q) {
      f16x8 b2;
#pragma unroll
      for (int b = 0; b < 8; ++b)
        b2[b] = (_Float16)acc[2 * q + (b >> 2)][ni][b & 3];
      d2[ni] = __builtin_amdgcn_mfma_f32_16x16x32_f16(a2[q], b2, d2[ni], 0, 0, 0);
    }
  }

  // All D2 rows equal; lane holds S[t = t_half + ni*16 + l15] in d2[ni][0].
  if (lg == 0) {
#pragma unroll
    for (int ni = 0; ni < 4; ++ni)
      red[(wc << 6) + (ni << 4) + l15][wr] = d2[ni][0];
  }
  __syncthreads();
  if (tid < 128) {
    float v = red[tid][0] + red[tid][1];
    sc2[((size_t)((h * 32 + n) * 2 + eb) << 11) + (tb << 7) + tid] = v;
  }
}

// ---------------------------------------------------------------------------
// Softmax over T per (h,n) row: adds the two eb partials, result -> eb=0 slot.
// ---------------------------------------------------------------------------
__global__ void k_softmax(float* __restrict__ sc2) {
  __shared__ float sm[8];
  const int row = blockIdx.x, tid = threadIdx.x;
  float* b0 = sc2 + ((size_t)row << 12);
  const float* b1 = b0 + 2048;
  f4 a = *(const f4*)(b0 + tid * 8);
  f4 b = *(const f4*)(b0 + tid * 8 + 4);
  f4 a1 = *(const f4*)(b1 + tid * 8);
  f4 b1v = *(const f4*)(b1 + tid * 8 + 4);
  a.x += a1.x; a.y += a1.y; a.z += a1.z; a.w += a1.w;
  b.x += b1v.x; b.y += b1v.y; b.z += b1v.z; b.w += b1v.w;
  float m = fmaxf(fmaxf(fmaxf(a.x, a.y), fmaxf(a.z, a.w)),
                  fmaxf(fmaxf(b.x, b.y), fmaxf(b.z, b.w)));
#pragma unroll
  for (int o = 1; o < 64; o <<= 1) m = fmaxf(m, __shfl_xor(m, o));
  if ((tid & 63) == 0) sm[tid >> 6] = m;
  __syncthreads();
  m = fmaxf(fmaxf(sm[0], sm[1]), fmaxf(sm[2], sm[3]));
  a.x = __expf(a.x - m); a.y = __expf(a.y - m); a.z = __expf(a.z - m); a.w = __expf(a.w - m);
  b.x = __expf(b.x - m); b.y = __expf(b.y - m); b.z = __expf(b.z - m); b.w = __expf(b.w - m);
  float s = a.x + a.y + a.z + a.w + b.x + b.y + b.z + b.w;
#pragma unroll
  for (int o = 1; o < 64; o <<= 1) s += __shfl_xor(s, o);
  if ((tid & 63) == 0) sm[4 + (tid >> 6)] = s;
  __syncthreads();
  s = sm[4] + sm[5] + sm[6] + sm[7];
  float inv = 1.f / s;
  a.x *= inv; a.y *= inv; a.z *= inv; a.w *= inv;
  b.x *= inv; b.y *= inv; b.z *= inv; b.w *= inv;
  *(f4*)(b0 + tid * 8) = a;
  *(f4*)(b0 + tid * 8 + 4) = b;
}

// ---------------------------------------------------------------------------
// Partial rep over t-slices of 128: rp[n][sl][h*256+d]; probs at stride 4096.
// ---------------------------------------------------------------------------
__global__ void k_rep(const float* __restrict__ mv, const float* __restrict__ p,
                      float* __restrict__ rp) {
  __shared__ float pl[8][128];
  const int b = blockIdx.x;
  const int n = b >> 4, sl = b & 15;
  const int tid = threadIdx.x;
  for (int i = tid; i < 1024; i += 256) {
    int h = i >> 7, t = i & 127;
    pl[h][t] = p[(((size_t)h * 32 + n) << 12) + sl * 128 + t];
  }
  __syncthreads();
  float r[8] = {0.f, 0.f, 0.f, 0.f, 0.f, 0.f, 0.f, 0.f};
  const float* src = mv + (((size_t)n << 11) + sl * 128) * DD + tid;
#pragma unroll 4
  for (int tt = 0; tt < 128; ++tt) {
    float v = src[(size_t)tt * DD];
#pragma unroll
    for (int h = 0; h < 8; ++h) r[h] = fmaf(pl[h][tt], v, r[h]);
  }
  float* dst = rp + (((size_t)n * 16 + sl) << 11) + tid;
#pragma unroll
  for (int h = 0; h < 8; ++h) dst[h * 256] = r[h];
}

// ---------------------------------------------------------------------------
// out[n][i] = b[i] + sum_j concat[n][j] * Wo_w[i][j]
// ---------------------------------------------------------------------------
__global__ void k_out(const float* __restrict__ rp, const float* __restrict__ w,
                      const float* __restrict__ bias, float* __restrict__ out) {
  __shared__ float c[2048];
  const int n = blockIdx.x, tid = threadIdx.x;
  for (int j = tid; j < 2048; j += 256) {
    float s = 0.f;
#pragma unroll
    for (int sl = 0; sl < 16; ++sl) s += rp[(((size_t)n * 16 + sl) << 11) + j];
    c[j] = s;
  }
  __syncthreads();
  float acc = bias[tid];
  const f4* wrow = (const f4*)(w + (size_t)tid * 2048);
  const f4* cc = (const f4*)c;
  for (int j = 0; j < 512; ++j) {
    f4 wv = wrow[j];
    f4 cv = cc[j];
    acc += wv.x * cv.x + wv.y * cv.y + wv.z * cv.z + wv.w * cv.w;
  }
  out[n * 256 + tid] = acc;
}

extern "C" void kernel_launch(void* const* d_in, const int* in_sizes, int n_in,
                              void* d_out, int out_size, void* d_ws, size_t ws_size,
                              hipStream_t stream) {
  const float* ok  = (const float*)d_in[0];
  const float* mk  = (const float*)d_in[1];
  const float* mv  = (const float*)d_in[2];
  const float* wm  = (const float*)d_in[3];
  const float* wow = (const float*)d_in[4];
  const float* wob = (const float*)d_in[5];
  float* out = (float*)d_out;
  char* ws = (char*)d_ws;

  // ws: [0,4MB) sc2 partials/probs | [4,5MB) packB | [8,16MB) rep | [16,48MB) packA
  float* sc2 = (float*)ws;
  u16* pb    = (u16*)(ws + (4u << 20));
  float* rp  = (float*)(ws + (8u << 20));
  u16* pa    = (u16*)(ws + (16u << 20));

  hipLaunchKernelGGL(k_pack,    dim3(8448), dim3(256), 0, stream, mk, wm, pa, pb);
  hipLaunchKernelGGL(k_scoresf, dim3(8192), dim3(256), 0, stream, ok, pa, pb, sc2);
  hipLaunchKernelGGL(k_softmax, dim3(256),  dim3(256), 0, stream, sc2);
  hipLaunchKernelGGL(k_rep,     dim3(512),  dim3(256), 0, stream, mv, sc2, rp);
  hipLaunchKernelGGL(k_out,     dim3(32),   dim3(256), 0, stream, rp, wow, wob, out);
}

// Round 8
// 220.378 us; speedup vs baseline: 2.9046x; 1.0068x over previous
//
#include <hip/hip_runtime.h>

#define HH 8
#define NN 32
#define TT 2048
#define DD 256

typedef float f4 __attribute__((ext_vector_type(4)));
typedef float f32x4 __attribute__((ext_vector_type(4)));
typedef _Float16 f16x8 __attribute__((ext_vector_type(8)));
typedef unsigned short u16;
typedef u16 u16x8 __attribute__((ext_vector_type(8)));

__device__ __forceinline__ u16 f2h(float x) {
  _Float16 h = (_Float16)x;
  return *(u16*)&h;
}

// Fast tanh: 1 - 2*rcp(exp(2|x|)+1), sign via copysign. 2 trans + ~6 full-rate.
__device__ __forceinline__ float ftanh(float x) {
  float ax = __builtin_fabsf(x);
  float e = __expf(ax + ax);
  float t = 1.f - __fdividef(2.f, e + 1.f);
  return __builtin_copysignf(t, x);
}

__device__ __forceinline__ void gl_lds16(const void* g, void* l) {
  __builtin_amdgcn_global_load_lds((const __attribute__((address_space(1))) unsigned*)g,
                                   (__attribute__((address_space(3))) unsigned*)l, 16, 0, 0);
}

// ===========================================================================
// Packed operand layout (verified R2-R6), 128-row regions:
// per 8KB region = [128 rows][32 k] f16:
//   line = row>>1 (128B lines of 8 x 16B slots), line in [0,64);
//   slot pos = (ksl | ((row&1)<<2)) ^ (line&7)   (XOR bank swizzle);
//   within slot, u16 j holds k = ks*32 + ksl*4 + {0,1,2,3,16,17,18,19}[j]
//   (k-pattern of mfma_f32_16x16x32 operand fragments, verified R0/R1).
// Regions are operand-role agnostic ([row][k]); row = the non-K dim.
// ===========================================================================

// Merged pack: bid<8192 -> mk [N][T][D] -> pa [n*16+tb][ks(8)][4096 u16] (32MB)
//              bid>=8192 -> Wm [H][256e][256d] -> pb [h*2+eb][ks(8)][4096 u16] (1MB)
__global__ void k_pack(const float* __restrict__ mk, const float* __restrict__ wm,
                       u16* __restrict__ pa, u16* __restrict__ pb) {
  const int bid = blockIdx.x;
  if (bid < 8192) {
    int u = bid * 256 + threadIdx.x;
    int pos  = u & 7;
    int line = (u >> 3) & 63;
    int ks   = (u >> 9) & 7;
    int tb   = (u >> 12) & 15;
    int n    = u >> 16;
    int origpos = pos ^ (line & 7);
    int r   = (line << 1) + (origpos >> 2);
    int ksl = origpos & 3;
    int kb  = (ks << 5) + (ksl << 2);
    const float* src = mk + (((size_t)n * TT + (tb << 7) + r) << 8) + kb;
    f4 v0 = *(const f4*)src;
    f4 v1 = *(const f4*)(src + 16);
    u16 hv[8] = {f2h(v0.x), f2h(v0.y), f2h(v0.z), f2h(v0.w),
                 f2h(v1.x), f2h(v1.y), f2h(v1.z), f2h(v1.w)};
    *(u16x8*)(pa + ((size_t)u << 3)) = *(u16x8*)hv;
  } else {
    int u = (bid - 8192) * 256 + threadIdx.x;
    int pos  = u & 7;
    int line = (u >> 3) & 63;
    int ks   = (u >> 9) & 7;
    int eb   = (u >> 12) & 1;
    int h    = u >> 13;
    int origpos = pos ^ (line & 7);
    int el  = (line << 1) + (origpos >> 2);
    int e   = (eb << 7) + el;
    int ksl = origpos & 3;
    int kb  = (ks << 5) + (ksl << 2);
    const float* src = wm + (((size_t)h * 256 + e) << 8) + kb;
    f4 v0 = *(const f4*)src;
    f4 v1 = *(const f4*)(src + 16);
    u16 hv[8] = {f2h(v0.x), f2h(v0.y), f2h(v0.z), f2h(v0.w),
                 f2h(v1.x), f2h(v1.y), f2h(v1.z), f2h(v1.w)};
    *(u16x8*)(pb + ((size_t)u << 3)) = *(u16x8*)hv;
  }
}

// ---------------------------------------------------------------------------
// sc2[(h*32+n)*2+eb][t] = sum_{e in eb-half} tanh(Wm[h] @ mk[n,t])[e] * ok[n,e]
// SWAPPED operands: A=Wm (M=e 128), B=mk (N=t 128) -> acc = P^T[e][t].
// Epilogue dot over e done with a SECOND MFMA (acc regs are lane-local
// B-operand k-fragments); no shfl-reduce.
// Double-buffered LDS, stage(k+1) issued before compute(k): 1 barrier/step.
// ---------------------------------------------------------------------------
__global__ __launch_bounds__(256, 3) void k_scoresf(
    const float* __restrict__ ok, const u16* __restrict__ pa,
    const u16* __restrict__ pb, float* __restrict__ sc2) {
  __shared__ __align__(1024) u16 lds[2][8192];  // 2 x (mk 8KB | Wm 8KB)
  __shared__ float red[128][2];

  const int bid = blockIdx.x;
  const int h  = bid & 7;            // == XCD
  const int eb = (bid >> 3) & 1;
  const int tb = (bid >> 4) & 15;
  const int n  = bid >> 8;
  const int tid = threadIdx.x;
  const int wave = tid >> 6;
  const int lane = tid & 63;
  const int wr = wave >> 1, wc = wave & 1;   // wr: e-half, wc: t-half
  const int l15 = lane & 15, lg = lane >> 4;

  // fragment LDS offsets (u16 units): Wm = A operand (rows e), mk = B (rows t)
  int Woff[4], Moff[4];
#pragma unroll
  for (int mi = 0; mi < 4; ++mi) {
    int row = (wr << 6) + (mi << 4) + l15;
    int line = row >> 1;
    int pos = (lg | ((row & 1) << 2)) ^ (line & 7);
    Woff[mi] = 4096 + (line << 6) + (pos << 3);
  }
#pragma unroll
  for (int ni = 0; ni < 4; ++ni) {
    int row = (wc << 6) + (ni << 4) + l15;
    int line = row >> 1;
    int pos = (lg | ((row & 1) << 2)) ^ (line & 7);
    Moff[ni] = (line << 6) + (pos << 3);
  }

  const u16* abase = pa + ((size_t)(n * 16 + tb) << 15);
  const u16* bbase = pb + ((size_t)(h * 2 + eb) << 15);

  auto stage = [&](int ks, int cur) {
    u16* dst = &lds[cur][0];
#pragma unroll
    for (int j = 0; j < 4; ++j) {
      const int c = (j << 2) + wave;   // mk chunks 0..7, Wm chunks 8..15
      const u16* src = (j < 2 ? abase + (ks << 12) + (c << 9)
                              : bbase + (ks << 12) + ((c - 8) << 9)) + (lane << 3);
      gl_lds16(src, dst + (c << 9));
    }
  };

  f32x4 acc[4][4];
#pragma unroll
  for (int i = 0; i < 4; ++i)
#pragma unroll
    for (int j = 0; j < 4; ++j) acc[i][j] = (f32x4){0.f, 0.f, 0.f, 0.f};

  stage(0, 0);
  __syncthreads();                    // drains vmcnt(0)
#pragma unroll 1
  for (int ks = 0; ks < 8; ++ks) {
    const int cur = ks & 1;
    if (ks < 7) stage(ks + 1, cur ^ 1);   // overlap next-step loads w/ compute
    f16x8 wfr[4], mfr[4];
#pragma unroll
    for (int mi = 0; mi < 4; ++mi) wfr[mi] = *(const f16x8*)&lds[cur][Woff[mi]];
#pragma unroll
    for (int ni = 0; ni < 4; ++ni) mfr[ni] = *(const f16x8*)&lds[cur][Moff[ni]];
#pragma unroll
    for (int mi = 0; mi < 4; ++mi)
#pragma unroll
      for (int ni = 0; ni < 4; ++ni)
        acc[mi][ni] = __builtin_amdgcn_mfma_f32_16x16x32_f16(wfr[mi], mfr[ni], acc[mi][ni], 0, 0, 0);
    __syncthreads();                  // drains stage's vmcnt + sync reads
  }

  // Epilogue: S_partial[t] = sum_e tanh(P^T[e][t]) * ok[e]  via MFMA.
  // acc lane layout: e_row = mi*16 + lg*4 + j, t_col = l15 (verified C/D map).
  // B2 frag for (ni,q): elem b -> tanh(acc[2q+(b>>2)][ni][b&3]); k-pattern
  // k = lg*4 + (b&3) + 16*(b>>2) matches e rows lane-locally.
#pragma unroll
  for (int mi = 0; mi < 4; ++mi)
#pragma unroll
    for (int ni = 0; ni < 4; ++ni)
#pragma unroll
      for (int j = 0; j < 4; ++j) acc[mi][ni][j] = ftanh(acc[mi][ni][j]);

  // ok A-fragments (rows replicated): elem b -> ok[e_base + q*32 + lg*4 + (b&3) + 16*(b>>2)]
  f16x8 a2[2];
#pragma unroll
  for (int q = 0; q < 2; ++q) {
    const float* okb = ok + (n << 8) + (eb << 7) + (wr << 6) + (q << 5) + (lg << 2);
#pragma unroll
    for (int b = 0; b < 8; ++b)
      a2[q][b] = (_Float16)okb[(b & 3) + ((b >> 2) << 4)];
  }

  f32x4 d2[4];
#pragma unroll
  for (int ni = 0; ni < 4; ++ni) d2[ni] = (f32x4){0.f, 0.f, 0.f, 0.f};
#pragma unroll
  for (int ni = 0; ni < 4; ++ni) {
#pragma unroll
    for (int q = 0; q < 2; ++q) {
      f16x8 b2;
#pragma unroll
      for (int b = 0; b < 8; ++b)
        b2[b] = (_Float16)acc[2 * q + (b >> 2)][ni][b & 3];
      d2[ni] = __builtin_amdgcn_mfma_f32_16x16x32_f16(a2[q], b2, d2[ni], 0, 0, 0);
    }
  }

  // All D2 rows equal; lane holds S[t = t_half + ni*16 + l15] in d2[ni][0].
  if (lg == 0) {
#pragma unroll
    for (int ni = 0; ni < 4; ++ni)
      red[(wc << 6) + (ni << 4) + l15][wr] = d2[ni][0];
  }
  __syncthreads();
  if (tid < 128) {
    float v = red[tid][0] + red[tid][1];
    sc2[((size_t)((h * 32 + n) * 2 + eb) << 11) + (tb << 7) + tid] = v;
  }
}

// ---------------------------------------------------------------------------
// Softmax over T per (h,n) row: adds the two eb partials, result -> eb=0 slot.
// ---------------------------------------------------------------------------
__global__ void k_softmax(float* __restrict__ sc2) {
  __shared__ float sm[8];
  const int row = blockIdx.x, tid = threadIdx.x;
  float* b0 = sc2 + ((size_t)row << 12);
  const float* b1 = b0 + 2048;
  f4 a = *(const f4*)(b0 + tid * 8);
  f4 b = *(const f4*)(b0 + tid * 8 + 4);
  f4 a1 = *(const f4*)(b1 + tid * 8);
  f4 b1v = *(const f4*)(b1 + tid * 8 + 4);
  a.x += a1.x; a.y += a1.y; a.z += a1.z; a.w += a1.w;
  b.x += b1v.x; b.y += b1v.y; b.z += b1v.z; b.w += b1v.w;
  float m = fmaxf(fmaxf(fmaxf(a.x, a.y), fmaxf(a.z, a.w)),
                  fmaxf(fmaxf(b.x, b.y), fmaxf(b.z, b.w)));
#pragma unroll
  for (int o = 1; o < 64; o <<= 1) m = fmaxf(m, __shfl_xor(m, o));
  if ((tid & 63) == 0) sm[tid >> 6] = m;
  __syncthreads();
  m = fmaxf(fmaxf(sm[0], sm[1]), fmaxf(sm[2], sm[3]));
  a.x = __expf(a.x - m); a.y = __expf(a.y - m); a.z = __expf(a.z - m); a.w = __expf(a.w - m);
  b.x = __expf(b.x - m); b.y = __expf(b.y - m); b.z = __expf(b.z - m); b.w = __expf(b.w - m);
  float s = a.x + a.y + a.z + a.w + b.x + b.y + b.z + b.w;
#pragma unroll
  for (int o = 1; o < 64; o <<= 1) s += __shfl_xor(s, o);
  if ((tid & 63) == 0) sm[4 + (tid >> 6)] = s;
  __syncthreads();
  s = sm[4] + sm[5] + sm[6] + sm[7];
  float inv = 1.f / s;
  a.x *= inv; a.y *= inv; a.z *= inv; a.w *= inv;
  b.x *= inv; b.y *= inv; b.z *= inv; b.w *= inv;
  *(f4*)(b0 + tid * 8) = a;
  *(f4*)(b0 + tid * 8 + 4) = b;
}

// ---------------------------------------------------------------------------
// Partial rep over t-slices of 128: rp[n][sl][h*256+d]; probs at stride 4096.
// ---------------------------------------------------------------------------
__global__ void k_rep(const float* __restrict__ mv, const float* __restrict__ p,
                      float* __restrict__ rp) {
  __shared__ float pl[8][128];
  const int b = blockIdx.x;
  const int n = b >> 4, sl = b & 15;
  const int tid = threadIdx.x;
  for (int i = tid; i < 1024; i += 256) {
    int h = i >> 7, t = i & 127;
    pl[h][t] = p[(((size_t)h * 32 + n) << 12) + sl * 128 + t];
  }
  __syncthreads();
  float r[8] = {0.f, 0.f, 0.f, 0.f, 0.f, 0.f, 0.f, 0.f};
  const float* src = mv + (((size_t)n << 11) + sl * 128) * DD + tid;
#pragma unroll 4
  for (int tt = 0; tt < 128; ++tt) {
    float v = src[(size_t)tt * DD];
#pragma unroll
    for (int h = 0; h < 8; ++h) r[h] = fmaf(pl[h][tt], v, r[h]);
  }
  float* dst = rp + (((size_t)n * 16 + sl) << 11) + tid;
#pragma unroll
  for (int h = 0; h < 8; ++h) dst[h * 256] = r[h];
}

// ---------------------------------------------------------------------------
// out[n][i] = b[i] + sum_j concat[n][j] * Wo_w[i][j]
// ---------------------------------------------------------------------------
__global__ void k_out(const float* __restrict__ rp, const float* __restrict__ w,
                      const float* __restrict__ bias, float* __restrict__ out) {
  __shared__ float c[2048];
  const int n = blockIdx.x, tid = threadIdx.x;
  for (int j = tid; j < 2048; j += 256) {
    float s = 0.f;
#pragma unroll
    for (int sl = 0; sl < 16; ++sl) s += rp[(((size_t)n * 16 + sl) << 11) + j];
    c[j] = s;
  }
  __syncthreads();
  float acc = bias[tid];
  const f4* wrow = (const f4*)(w + (size_t)tid * 2048);
  const f4* cc = (const f4*)c;
  for (int j = 0; j < 512; ++j) {
    f4 wv = wrow[j];
    f4 cv = cc[j];
    acc += wv.x * cv.x + wv.y * cv.y + wv.z * cv.z + wv.w * cv.w;
  }
  out[n * 256 + tid] = acc;
}

extern "C" void kernel_launch(void* const* d_in, const int* in_sizes, int n_in,
                              void* d_out, int out_size, void* d_ws, size_t ws_size,
                              hipStream_t stream) {
  const float* ok  = (const float*)d_in[0];
  const float* mk  = (const float*)d_in[1];
  const float* mv  = (const float*)d_in[2];
  const float* wm  = (const float*)d_in[3];
  const float* wow = (const float*)d_in[4];
  const float* wob = (const float*)d_in[5];
  float* out = (float*)d_out;
  char* ws = (char*)d_ws;

  // ws: [0,4MB) sc2 partials/probs | [4,5MB) packB | [8,16MB) rep | [16,48MB) packA
  float* sc2 = (float*)ws;
  u16* pb    = (u16*)(ws + (4u << 20));
  float* rp  = (float*)(ws + (8u << 20));
  u16* pa    = (u16*)(ws + (16u << 20));

  hipLaunchKernelGGL(k_pack,    dim3(8448), dim3(256), 0, stream, mk, wm, pa, pb);
  hipLaunchKernelGGL(k_scoresf, dim3(8192), dim3(256), 0, stream, ok, pa, pb, sc2);
  hipLaunchKernelGGL(k_softmax, dim3(256),  dim3(256), 0, stream, sc2);
  hipLaunchKernelGGL(k_rep,     dim3(512),  dim3(256), 0, stream, mv, sc2, rp);
  hipLaunchKernelGGL(k_out,     dim3(32),   dim3(256), 0, stream, rp, wow, wob, out);
}

// Round 9
// 220.018 us; speedup vs baseline: 2.9093x; 1.0016x over previous
//
#include <hip/hip_runtime.h>

#define HH 8
#define NN 32
#define TT 2048
#define DD 256

typedef float f4 __attribute__((ext_vector_type(4)));
typedef float f32x4 __attribute__((ext_vector_type(4)));
typedef _Float16 f16x8 __attribute__((ext_vector_type(8)));
typedef unsigned short u16;
typedef u16 u16x8 __attribute__((ext_vector_type(8)));

__device__ __forceinline__ u16 f2h(float x) {
  _Float16 h = (_Float16)x;
  return *(u16*)&h;
}

// Fast tanh: 1 - 2*rcp(exp(2|x|)+1), sign via copysign. 2 trans + ~6 full-rate.
__device__ __forceinline__ float ftanh(float x) {
  float ax = __builtin_fabsf(x);
  float e = __expf(ax + ax);
  float t = 1.f - __fdividef(2.f, e + 1.f);
  return __builtin_copysignf(t, x);
}

__device__ __forceinline__ void gl_lds16(const void* g, void* l) {
  __builtin_amdgcn_global_load_lds((const __attribute__((address_space(1))) unsigned*)g,
                                   (__attribute__((address_space(3))) unsigned*)l, 16, 0, 0);
}

// ===========================================================================
// Packed operand layout (verified R2-R6), 128-row regions:
// per 8KB region = [128 rows][32 k] f16:
//   line = row>>1 (128B lines of 8 x 16B slots), line in [0,64);
//   slot pos = (ksl | ((row&1)<<2)) ^ (line&7)   (XOR bank swizzle);
//   within slot, u16 j holds k = ks*32 + ksl*4 + {0,1,2,3,16,17,18,19}[j]
//   (k-pattern of mfma_f32_16x16x32 operand fragments, verified R0/R1).
// Regions are operand-role agnostic ([row][k]); row = the non-K dim.
// ===========================================================================

// Merged pack: bid<8192 -> mk [N][T][D] -> pa [n*16+tb][ks(8)][4096 u16] (32MB)
//              bid>=8192 -> Wm [H][256e][256d] -> pb [h*2+eb][ks(8)][4096 u16] (1MB)
__global__ void k_pack(const float* __restrict__ mk, const float* __restrict__ wm,
                       u16* __restrict__ pa, u16* __restrict__ pb) {
  const int bid = blockIdx.x;
  if (bid < 8192) {
    int u = bid * 256 + threadIdx.x;
    int pos  = u & 7;
    int line = (u >> 3) & 63;
    int ks   = (u >> 9) & 7;
    int tb   = (u >> 12) & 15;
    int n    = u >> 16;
    int origpos = pos ^ (line & 7);
    int r   = (line << 1) + (origpos >> 2);
    int ksl = origpos & 3;
    int kb  = (ks << 5) + (ksl << 2);
    const float* src = mk + (((size_t)n * TT + (tb << 7) + r) << 8) + kb;
    f4 v0 = *(const f4*)src;
    f4 v1 = *(const f4*)(src + 16);
    u16 hv[8] = {f2h(v0.x), f2h(v0.y), f2h(v0.z), f2h(v0.w),
                 f2h(v1.x), f2h(v1.y), f2h(v1.z), f2h(v1.w)};
    *(u16x8*)(pa + ((size_t)u << 3)) = *(u16x8*)hv;
  } else {
    int u = (bid - 8192) * 256 + threadIdx.x;
    int pos  = u & 7;
    int line = (u >> 3) & 63;
    int ks   = (u >> 9) & 7;
    int eb   = (u >> 12) & 1;
    int h    = u >> 13;
    int origpos = pos ^ (line & 7);
    int el  = (line << 1) + (origpos >> 2);
    int e   = (eb << 7) + el;
    int ksl = origpos & 3;
    int kb  = (ks << 5) + (ksl << 2);
    const float* src = wm + (((size_t)h * 256 + e) << 8) + kb;
    f4 v0 = *(const f4*)src;
    f4 v1 = *(const f4*)(src + 16);
    u16 hv[8] = {f2h(v0.x), f2h(v0.y), f2h(v0.z), f2h(v0.w),
                 f2h(v1.x), f2h(v1.y), f2h(v1.z), f2h(v1.w)};
    *(u16x8*)(pb + ((size_t)u << 3)) = *(u16x8*)hv;
  }
}

// ---------------------------------------------------------------------------
// sc2[(h*32+n)*2+eb][t] = sum_{e in eb-half} tanh(Wm[h] @ mk[n,t])[e] * ok[n,e]
// SWAPPED operands: A=Wm (M=e 128), B=mk (N=t 128) -> acc = P^T[e][t].
// Epilogue dot over e done with a SECOND MFMA (acc regs are lane-local
// B-operand k-fragments); no shfl-reduce.
// Double-buffered LDS, stage(k+1) issued before compute(k): 1 barrier/step.
// ---------------------------------------------------------------------------
__global__ __launch_bounds__(256, 3) void k_scoresf(
    const float* __restrict__ ok, const u16* __restrict__ pa,
    const u16* __restrict__ pb, float* __restrict__ sc2) {
  __shared__ __align__(1024) u16 lds[2][8192];  // 2 x (mk 8KB | Wm 8KB)
  __shared__ float red[128][2];

  const int bid = blockIdx.x;
  const int h  = bid & 7;            // == XCD
  const int eb = (bid >> 3) & 1;
  const int tb = (bid >> 4) & 15;
  const int n  = bid >> 8;
  const int tid = threadIdx.x;
  const int wave = tid >> 6;
  const int lane = tid & 63;
  const int wr = wave >> 1, wc = wave & 1;   // wr: e-half, wc: t-half
  const int l15 = lane & 15, lg = lane >> 4;

  // fragment LDS offsets (u16 units): Wm = A operand (rows e), mk = B (rows t)
  int Woff[4], Moff[4];
#pragma unroll
  for (int mi = 0; mi < 4; ++mi) {
    int row = (wr << 6) + (mi << 4) + l15;
    int line = row >> 1;
    int pos = (lg | ((row & 1) << 2)) ^ (line & 7);
    Woff[mi] = 4096 + (line << 6) + (pos << 3);
  }
#pragma unroll
  for (int ni = 0; ni < 4; ++ni) {
    int row = (wc << 6) + (ni << 4) + l15;
    int line = row >> 1;
    int pos = (lg | ((row & 1) << 2)) ^ (line & 7);
    Moff[ni] = (line << 6) + (pos << 3);
  }

  const u16* abase = pa + ((size_t)(n * 16 + tb) << 15);
  const u16* bbase = pb + ((size_t)(h * 2 + eb) << 15);

  auto stage = [&](int ks, int cur) {
    u16* dst = &lds[cur][0];
#pragma unroll
    for (int j = 0; j < 4; ++j) {
      const int c = (j << 2) + wave;   // mk chunks 0..7, Wm chunks 8..15
      const u16* src = (j < 2 ? abase + (ks << 12) + (c << 9)
                              : bbase + (ks << 12) + ((c - 8) << 9)) + (lane << 3);
      gl_lds16(src, dst + (c << 9));
    }
  };

  f32x4 acc[4][4];
#pragma unroll
  for (int i = 0; i < 4; ++i)
#pragma unroll
    for (int j = 0; j < 4; ++j) acc[i][j] = (f32x4){0.f, 0.f, 0.f, 0.f};

  stage(0, 0);
  __syncthreads();                    // drains vmcnt(0)
#pragma unroll 1
  for (int ks = 0; ks < 8; ++ks) {
    const int cur = ks & 1;
    if (ks < 7) stage(ks + 1, cur ^ 1);   // overlap next-step loads w/ compute
    f16x8 wfr[4], mfr[4];
#pragma unroll
    for (int mi = 0; mi < 4; ++mi) wfr[mi] = *(const f16x8*)&lds[cur][Woff[mi]];
#pragma unroll
    for (int ni = 0; ni < 4; ++ni) mfr[ni] = *(const f16x8*)&lds[cur][Moff[ni]];
#pragma unroll
    for (int mi = 0; mi < 4; ++mi)
#pragma unroll
      for (int ni = 0; ni < 4; ++ni)
        acc[mi][ni] = __builtin_amdgcn_mfma_f32_16x16x32_f16(wfr[mi], mfr[ni], acc[mi][ni], 0, 0, 0);
    __syncthreads();                  // drains stage's vmcnt + sync reads
  }

  // Epilogue: S_partial[t] = sum_e tanh(P^T[e][t]) * ok[e]  via MFMA.
  // acc lane layout: e_row = mi*16 + lg*4 + j, t_col = l15 (verified C/D map).
  // B2 frag for (ni,q): elem b -> tanh(acc[2q+(b>>2)][ni][b&3]); k-pattern
  // k = lg*4 + (b&3) + 16*(b>>2) matches e rows lane-locally.
#pragma unroll
  for (int mi = 0; mi < 4; ++mi)
#pragma unroll
    for (int ni = 0; ni < 4; ++ni)
#pragma unroll
      for (int j = 0; j < 4; ++j) acc[mi][ni][j] = ftanh(acc[mi][ni][j]);

  // ok A-fragments (rows replicated): elem b -> ok[e_base + q*32 + lg*4 + (b&3) + 16*(b>>2)]
  f16x8 a2[2];
#pragma unroll
  for (int q = 0; q < 2; ++q) {
    const float* okb = ok + (n << 8) + (eb << 7) + (wr << 6) + (q << 5) + (lg << 2);
#pragma unroll
    for (int b = 0; b < 8; ++b)
      a2[q][b] = (_Float16)okb[(b & 3) + ((b >> 2) << 4)];
  }

  f32x4 d2[4];
#pragma unroll
  for (int ni = 0; ni < 4; ++ni) d2[ni] = (f32x4){0.f, 0.f, 0.f, 0.f};
#pragma unroll
  for (int ni = 0; ni < 4; ++ni) {
#pragma unroll
    for (int q = 0; q < 2; ++q) {
      f16x8 b2;
#pragma unroll
      for (int b = 0; b < 8; ++b)
        b2[b] = (_Float16)acc[2 * q + (b >> 2)][ni][b & 3];
      d2[ni] = __builtin_amdgcn_mfma_f32_16x16x32_f16(a2[q], b2, d2[ni], 0, 0, 0);
    }
  }

  // All D2 rows equal; lane holds S[t = t_half + ni*16 + l15] in d2[ni][0].
  if (lg == 0) {
#pragma unroll
    for (int ni = 0; ni < 4; ++ni)
      red[(wc << 6) + (ni << 4) + l15][wr] = d2[ni][0];
  }
  __syncthreads();
  if (tid < 128) {
    float v = red[tid][0] + red[tid][1];
    sc2[((size_t)((h * 32 + n) * 2 + eb) << 11) + (tb << 7) + tid] = v;
  }
}

// ---------------------------------------------------------------------------
// Softmax over T per (h,n) row: adds the two eb partials, result -> eb=0 slot.
// ---------------------------------------------------------------------------
__global__ void k_softmax(float* __restrict__ sc2) {
  __shared__ float sm[8];
  const int row = blockIdx.x, tid = threadIdx.x;
  float* b0 = sc2 + ((size_t)row << 12);
  const float* b1 = b0 + 2048;
  f4 a = *(const f4*)(b0 + tid * 8);
  f4 b = *(const f4*)(b0 + tid * 8 + 4);
  f4 a1 = *(const f4*)(b1 + tid * 8);
  f4 b1v = *(const f4*)(b1 + tid * 8 + 4);
  a.x += a1.x; a.y += a1.y; a.z += a1.z; a.w += a1.w;
  b.x += b1v.x; b.y += b1v.y; b.z += b1v.z; b.w += b1v.w;
  float m = fmaxf(fmaxf(fmaxf(a.x, a.y), fmaxf(a.z, a.w)),
                  fmaxf(fmaxf(b.x, b.y), fmaxf(b.z, b.w)));
#pragma unroll
  for (int o = 1; o < 64; o <<= 1) m = fmaxf(m, __shfl_xor(m, o));
  if ((tid & 63) == 0) sm[tid >> 6] = m;
  __syncthreads();
  m = fmaxf(fmaxf(sm[0], sm[1]), fmaxf(sm[2], sm[3]));
  a.x = __expf(a.x - m); a.y = __expf(a.y - m); a.z = __expf(a.z - m); a.w = __expf(a.w - m);
  b.x = __expf(b.x - m); b.y = __expf(b.y - m); b.z = __expf(b.z - m); b.w = __expf(b.w - m);
  float s = a.x + a.y + a.z + a.w + b.x + b.y + b.z + b.w;
#pragma unroll
  for (int o = 1; o < 64; o <<= 1) s += __shfl_xor(s, o);
  if ((tid & 63) == 0) sm[4 + (tid >> 6)] = s;
  __syncthreads();
  s = sm[4] + sm[5] + sm[6] + sm[7];
  float inv = 1.f / s;
  a.x *= inv; a.y *= inv; a.z *= inv; a.w *= inv;
  b.x *= inv; b.y *= inv; b.z *= inv; b.w *= inv;
  *(f4*)(b0 + tid * 8) = a;
  *(f4*)(b0 + tid * 8 + 4) = b;
}

// ---------------------------------------------------------------------------
// Partial rep over t-slices of 128: rp[n][sl][h*256+d]; probs at stride 4096.
// ---------------------------------------------------------------------------
__global__ void k_rep(const float* __restrict__ mv, const float* __restrict__ p,
                      float* __restrict__ rp) {
  __shared__ float pl[8][128];
  const int b = blockIdx.x;
  const int n = b >> 4, sl = b & 15;
  const int tid = threadIdx.x;
  for (int i = tid; i < 1024; i += 256) {
    int h = i >> 7, t = i & 127;
    pl[h][t] = p[(((size_t)h * 32 + n) << 12) + sl * 128 + t];
  }
  __syncthreads();
  float r[8] = {0.f, 0.f, 0.f, 0.f, 0.f, 0.f, 0.f, 0.f};
  const float* src = mv + (((size_t)n << 11) + sl * 128) * DD + tid;
#pragma unroll 4
  for (int tt = 0; tt < 128; ++tt) {
    float v = src[(size_t)tt * DD];
#pragma unroll
    for (int h = 0; h < 8; ++h) r[h] = fmaf(pl[h][tt], v, r[h]);
  }
  float* dst = rp + (((size_t)n * 16 + sl) << 11) + tid;
#pragma unroll
  for (int h = 0; h < 8; ++h) dst[h * 256] = r[h];
}

// ---------------------------------------------------------------------------
// out[n][i] = b[i] + sum_j concat[n][j] * Wo_w[i][j]
// ---------------------------------------------------------------------------
__global__ void k_out(const float* __restrict__ rp, const float* __restrict__ w,
                      const float* __restrict__ bias, float* __restrict__ out) {
  __shared__ float c[2048];
  const int n = blockIdx.x, tid = threadIdx.x;
  for (int j = tid; j < 2048; j += 256) {
    float s = 0.f;
#pragma unroll
    for (int sl = 0; sl < 16; ++sl) s += rp[(((size_t)n * 16 + sl) << 11) + j];
    c[j] = s;
  }
  __syncthreads();
  float acc = bias[tid];
  const f4* wrow = (const f4*)(w + (size_t)tid * 2048);
  const f4* cc = (const f4*)c;
  for (int j = 0; j < 512; ++j) {
    f4 wv = wrow[j];
    f4 cv = cc[j];
    acc += wv.x * cv.x + wv.y * cv.y + wv.z * cv.z + wv.w * cv.w;
  }
  out[n * 256 + tid] = acc;
}

extern "C" void kernel_launch(void* const* d_in, const int* in_sizes, int n_in,
                              void* d_out, int out_size, void* d_ws, size_t ws_size,
                              hipStream_t stream) {
  const float* ok  = (const float*)d_in[0];
  const float* mk  = (const float*)d_in[1];
  const float* mv  = (const float*)d_in[2];
  const float* wm  = (const float*)d_in[3];
  const float* wow = (const float*)d_in[4];
  const float* wob = (const float*)d_in[5];
  float* out = (float*)d_out;
  char* ws = (char*)d_ws;

  // ws: [0,4MB) sc2 partials/probs | [4,5MB) packB | [8,16MB) rep | [16,48MB) packA
  float* sc2 = (float*)ws;
  u16* pb    = (u16*)(ws + (4u << 20));
  float* rp  = (float*)(ws + (8u << 20));
  u16* pa    = (u16*)(ws + (16u << 20));

  hipLaunchKernelGGL(k_pack,    dim3(8448), dim3(256), 0, stream, mk, wm, pa, pb);
  hipLaunchKernelGGL(k_scoresf, dim3(8192), dim3(256), 0, stream, ok, pa, pb, sc2);
  hipLaunchKernelGGL(k_softmax, dim3(256),  dim3(256), 0, stream, sc2);
  hipLaunchKernelGGL(k_rep,     dim3(512),  dim3(256), 0, stream, mv, sc2, rp);
  hipLaunchKernelGGL(k_out,     dim3(32),   dim3(256), 0, stream, rp, wow, wob, out);
}